// Round 2
// baseline (2248.206 us; speedup 1.0000x reference)
//
#include <hip/hip_runtime.h>
#include <math.h>

#define G_    64
#define N_    512
#define H_    64
#define NT_   32768
#define ET_   1048576
#define EPG_  16384      // edges per graph
#define KP_   359
#define NP2_  22976
#define FIN_  128

// ---------------- e = coords @ pos_W + pos_b ----------------
__global__ void k_e(const float* __restrict__ coords, const float* __restrict__ posW,
                    const float* __restrict__ posb, float* __restrict__ e) {
    int gid = blockIdx.x * 256 + threadIdx.x;     // NT*64 threads
    int n = gid >> 6, c = gid & 63;
    float s = posb[c]
            + coords[n*3+0] * posW[0*64+c]
            + coords[n*3+1] * posW[1*64+c]
            + coords[n*3+2] * posW[2*64+c];
    e[gid] = s;
}

// ---------------- dual GEMM: outA = in@Wa, outB = in@Wb + bias ----------------
__global__ void k_gemm_dual(const float* __restrict__ in, int K,
                            const float* __restrict__ Wa, const float* __restrict__ Wb,
                            const float* __restrict__ bias,
                            float* __restrict__ outA, float* __restrict__ outB) {
    __shared__ float inT[16 * FIN_];
    int row0 = blockIdx.x * 16;
    int t = threadIdx.x;
    for (int idx = t; idx < 16 * K; idx += 256) inT[idx] = in[row0 * K + idx];
    __syncthreads();
    int c = t & 63, rb = t >> 6;
    for (int rr = 0; rr < 4; rr++) {
        int r = rb * 4 + rr;
        float accA = 0.f, accB = bias[c];
        const float* ip = inT + r * K;
        for (int k = 0; k < K; k++) {
            float a = ip[k];
            accA += a * Wa[k*64 + c];
            accB += a * Wb[k*64 + c];
        }
        outA[(row0 + r)*64 + c] = accA;
        outB[(row0 + r)*64 + c] = accB;
    }
}

// ---------------- stage-1 edge scatter, wave-per-edge-pair, 32-ch LDS tile ----------------
// target 0: Ae[row]  += ea * e[col]      target 1: agg[col] += y[row]
__global__ __launch_bounds__(1024)
void k_scat1(const int* __restrict__ row, const int* __restrict__ col,
             const float* __restrict__ ea,
             const float* __restrict__ e, const float* __restrict__ y,
             float* __restrict__ Ae, float* __restrict__ agg) {
    __shared__ float tile[N_ * 32];                 // 64 KB
    int half = blockIdx.x, target = blockIdx.y, g = blockIdx.z;
    int t = threadIdx.x;
    for (int i = t; i < N_ * 32; i += 1024) tile[i] = 0.f;
    __syncthreads();
    int wave = t >> 6, lane = t & 63;
    int ch = lane & 31, sub = lane >> 5;            // sub: which edge of the pair
    int c0 = half * 32;
    int ebase = g * EPG_;
    if (target == 0) {
        for (int b = wave * 64; b < EPG_; b += 1024) {
            int eidx = ebase + b + lane;
            int   r64 = row[eidx];
            int   c64 = col[eidx];
            float w64 = ea[eidx];
            #pragma unroll 4
            for (int j = 0; j < 64; j += 2) {
                int jj = j + sub;
                int   rj = __shfl(r64, jj) & (N_ - 1);
                int   cj = __shfl(c64, jj);
                float wj = __shfl(w64, jj);
                atomicAdd(&tile[rj * 32 + ch], wj * e[cj*64 + c0 + ch]);
            }
        }
    } else {
        for (int b = wave * 64; b < EPG_; b += 1024) {
            int eidx = ebase + b + lane;
            int r64 = row[eidx];
            int c64 = col[eidx];
            #pragma unroll 4
            for (int j = 0; j < 64; j += 2) {
                int jj = j + sub;
                int rj = __shfl(r64, jj);
                int cj = __shfl(c64, jj) & (N_ - 1);
                atomicAdd(&tile[cj * 32 + ch], y[rj*64 + c0 + ch]);
            }
        }
    }
    __syncthreads();
    int nbase = g * N_;
    float* out = (target == 0) ? Ae : agg;
    for (int i = t; i < N_ * 32; i += 1024) {
        int n = i >> 5, cc = i & 31;
        out[(nbase + n)*64 + c0 + cc] = tile[i];
    }
}

// ---------------- deg[col] += 1 over all edges of a graph ----------------
__global__ void k_deg1(const int* __restrict__ col, float* __restrict__ deg) {
    __shared__ float dgT[N_];
    int g = blockIdx.x, t = threadIdx.x;
    for (int i = t; i < N_; i += 256) dgT[i] = 0.f;
    __syncthreads();
    int ebase = g * EPG_;
    for (int i = t; i < EPG_; i += 256)
        atomicAdd(&dgT[col[ebase + i] & (N_ - 1)], 1.0f);
    __syncthreads();
    int nbase = g * N_;
    for (int i = t; i < N_; i += 256) deg[nbase + i] = dgT[i];
}

// ---------------- stage-2 Ae2 scatter: Ae2[s2] += e[col] (valid edges) ----------------
__global__ __launch_bounds__(1024)
void k_scat2a(const int* __restrict__ row, const int* __restrict__ col,
              const int* __restrict__ node_map, const float* __restrict__ e,
              float* __restrict__ Ae2) {
    __shared__ float tile[KP_ * 32];                // ~45 KB
    int half = blockIdx.x, g = blockIdx.y;
    int t = threadIdx.x;
    for (int i = t; i < KP_ * 32; i += 1024) tile[i] = 0.f;
    __syncthreads();
    int wave = t >> 6, lane = t & 63;
    int ch = lane & 31, sub = lane >> 5;
    int c0 = half * 32;
    int ebase = g * EPG_, pbase = g * KP_;
    for (int b = wave * 64; b < EPG_; b += 1024) {
        int eidx = ebase + b + lane;
        int c64 = col[eidx];
        int s2  = node_map[row[eidx]];
        int t2  = node_map[c64];
        int m64 = (s2 >= 0 && t2 >= 0) ? (s2 - pbase) : -1;
        #pragma unroll 4
        for (int j = 0; j < 64; j += 2) {
            int jj = j + sub;
            int mj = __shfl(m64, jj);
            int cj = __shfl(c64, jj);
            if (mj >= 0)
                atomicAdd(&tile[mj * 32 + ch], e[cj*64 + c0 + ch]);
        }
    }
    __syncthreads();
    for (int i = t; i < KP_ * 32; i += 1024) {
        int n = i >> 5, cc = i & 31;
        Ae2[(pbase + n)*64 + c0 + cc] = tile[i];
    }
}

// ---------------- stage-2 agg scatter: agg2[t2] += y2[s2] (valid edges) ----------------
__global__ __launch_bounds__(1024)
void k_scat2b(const int* __restrict__ row, const int* __restrict__ col,
              const int* __restrict__ node_map, const float* __restrict__ y2,
              float* __restrict__ agg2) {
    __shared__ float tile[KP_ * 32];
    int half = blockIdx.x, g = blockIdx.y;
    int t = threadIdx.x;
    for (int i = t; i < KP_ * 32; i += 1024) tile[i] = 0.f;
    __syncthreads();
    int wave = t >> 6, lane = t & 63;
    int ch = lane & 31, sub = lane >> 5;
    int c0 = half * 32;
    int ebase = g * EPG_, pbase = g * KP_;
    for (int b = wave * 64; b < EPG_; b += 1024) {
        int eidx = ebase + b + lane;
        int s2 = node_map[row[eidx]];
        int t2 = node_map[col[eidx]];
        int m64 = (s2 >= 0 && t2 >= 0) ? (t2 - pbase) : -1;
        #pragma unroll 4
        for (int j = 0; j < 64; j += 2) {
            int jj = j + sub;
            int mj = __shfl(m64, jj);
            int sj = __shfl(s2, jj);
            if (mj >= 0)
                atomicAdd(&tile[mj * 32 + ch], y2[sj*64 + c0 + ch]);
        }
    }
    __syncthreads();
    for (int i = t; i < KP_ * 32; i += 1024) {
        int n = i >> 5, cc = i & 31;
        agg2[(pbase + n)*64 + c0 + cc] = tile[i];
    }
}

// ---------------- deg2[t2] += 1 over valid edges ----------------
__global__ void k_deg2(const int* __restrict__ row, const int* __restrict__ col,
                       const int* __restrict__ node_map, float* __restrict__ deg2) {
    __shared__ float dgT[KP_];
    int g = blockIdx.x, t = threadIdx.x;
    for (int i = t; i < KP_; i += 256) dgT[i] = 0.f;
    __syncthreads();
    int ebase = g * EPG_, pbase = g * KP_;
    for (int i = t; i < EPG_; i += 256) {
        int s2 = node_map[row[ebase + i]];
        int t2 = node_map[col[ebase + i]];
        if (s2 >= 0 && t2 >= 0) atomicAdd(&dgT[t2 - pbase], 1.0f);
    }
    __syncthreads();
    for (int i = t; i < KP_; i += 256) deg2[pbase + i] = dgT[i];
}

// ---------------- per-node matvec: out[n,h] = sum_d Bk[cls[n]][h,d] * in[n,d] ----------------
__global__ void k_bkmv(const float* __restrict__ in, const int* __restrict__ cls,
                       const float* __restrict__ Bk, float* __restrict__ out) {
    __shared__ float inT[4 * 64];
    int node0 = blockIdx.x * 4;
    int t = threadIdx.x;
    inT[t] = in[node0 * 64 + t];
    __syncthreads();
    int c = t & 63, nb = t >> 6;
    int node = node0 + nb;
    const float* B  = Bk + cls[node] * 4096 + c * 64;
    const float* hv = inT + nb * 64;
    float acc = 0.f;
    #pragma unroll 8
    for (int d = 0; d < 64; d++) acc += B[d] * hv[d];
    out[node*64 + c] = acc;
}

// ---------------- propagate: out[n,i] = sum_j Bk[i,j]*(inA+inB)[n,j] + delta[n,i]*sum_j (inA+inB)[n,j]
__global__ void k_prop(const float* __restrict__ inA, const float* __restrict__ inB,
                       const float* __restrict__ delta, const int* __restrict__ cls,
                       const float* __restrict__ Bk, float* __restrict__ out) {
    __shared__ float hT[4 * 64];
    int node0 = blockIdx.x * 4;
    int t = threadIdx.x;
    float v = inA[node0*64 + t];
    if (inB) v += inB[node0*64 + t];
    hT[t] = v;
    __syncthreads();
    int c = t & 63, nb = t >> 6;
    int node = node0 + nb;
    float s = hT[nb*64 + c];
    for (int off = 32; off; off >>= 1) s += __shfl_down(s, off);
    s = __shfl(s, 0);
    const float* B  = Bk + cls[node] * 4096 + c * 64;
    const float* hv = hT + nb * 64;
    float acc = delta[node*64 + c] * s;
    #pragma unroll 8
    for (int d = 0; d < 64; d++) acc += B[d] * hv[d];
    out[node*64 + c] = acc;
}

// ---------------- graph_norm + elu (+ optional delta add) ----------------
__global__ void k_gn(const float* __restrict__ hself, const float* __restrict__ agg,
                     const float* __restrict__ deg,
                     const float* __restrict__ w, const float* __restrict__ b,
                     const float* __restrict__ ms,
                     const float* __restrict__ delta,   // nullable
                     float* __restrict__ out, int NPG) {
    __shared__ float red[4 * 64];
    __shared__ float meanS[64], istdS[64];
    int g = blockIdx.x, t = threadIdx.x;
    int c = t & 63, grp = t >> 6;
    int base = g * NPG;
    float s = 0.f;
    for (int n = grp; n < NPG; n += 4) {
        int node = base + n;
        s += hself[node*64 + c] + agg[node*64 + c] / fmaxf(deg[node], 1.0f);
    }
    red[t] = s;
    __syncthreads();
    if (grp == 0) meanS[c] = (red[c] + red[64+c] + red[128+c] + red[192+c]) / (float)NPG;
    __syncthreads();
    float mval = meanS[c] * ms[c];
    s = 0.f;
    for (int n = grp; n < NPG; n += 4) {
        int node = base + n;
        float v = hself[node*64 + c] + agg[node*64 + c] / fmaxf(deg[node], 1.0f) - mval;
        s += v * v;
    }
    red[t] = s;
    __syncthreads();
    if (grp == 0) {
        float var = (red[c] + red[64+c] + red[128+c] + red[192+c]) / (float)NPG;
        istdS[c] = rsqrtf(var + 1e-5f);
    }
    __syncthreads();
    float wv = w[c], bv = b[c], istd = istdS[c];
    for (int n = grp; n < NPG; n += 4) {
        int node = base + n;
        float v = hself[node*64 + c] + agg[node*64 + c] / fmaxf(deg[node], 1.0f) - mval;
        v = wv * v * istd + bv;
        v = v > 0.f ? v : expm1f(v);
        if (delta) v += delta[node*64 + c];
        out[node*64 + c] = v;
    }
}

// ---------------- top-k per graph (desc score, ties by lower idx) ----------------
__global__ void k_topk(const float* __restrict__ hp, const float* __restrict__ p,
                       const int* __restrict__ cls,
                       int* __restrict__ perm, float* __restrict__ tanhv,
                       int* __restrict__ node_map, int* __restrict__ class2) {
    __shared__ float key[N_];
    __shared__ int   idxS[N_];
    __shared__ float pS[64];
    __shared__ float nrm;
    int g = blockIdx.x, t = threadIdx.x;
    if (t < 64) pS[t] = p[t];
    __syncthreads();
    if (t == 0) {
        float s = 0.f;
        for (int i = 0; i < 64; i++) s += pS[i] * pS[i];
        nrm = sqrtf(s);
    }
    __syncthreads();
    {
        float acc = 0.f;
        const float* hv = hp + (size_t)(g*N_ + t) * 64;
        for (int cdx = 0; cdx < 64; cdx++) acc += hv[cdx] * pS[cdx];
        key[t]  = acc / nrm;
        idxS[t] = t;
    }
    __syncthreads();
    for (int k = 2; k <= N_; k <<= 1) {
        for (int j = k >> 1; j > 0; j >>= 1) {
            int i = t, ixj = i ^ j;
            if (ixj > i) {
                float ki = key[i], kj = key[ixj];
                int   ii = idxS[i], ij = idxS[ixj];
                bool before = (ki > kj) || (ki == kj && ii < ij);
                bool dir = ((i & k) == 0);
                if (dir ? !before : before) {
                    key[i] = kj; key[ixj] = ki;
                    idxS[i] = ij; idxS[ixj] = ii;
                }
            }
            __syncthreads();
        }
    }
    if (t < KP_) {
        int orig  = idxS[t];
        int gnode = g * N_ + orig;
        int pj    = g * KP_ + t;
        perm[pj]     = gnode;
        tanhv[pj]    = tanhf(key[t]);
        node_map[gnode] = pj;
        class2[pj]   = cls[gnode];
    }
}

// ---------------- pooled gather: h2[j] = hp[perm[j]] * tanhv[j] ----------------
__global__ void k_gather(const float* __restrict__ hp, const int* __restrict__ perm,
                         const float* __restrict__ tanhv, float* __restrict__ h2) {
    int gid = blockIdx.x * 256 + threadIdx.x;   // NP2*64
    int j = gid >> 6, c = gid & 63;
    h2[gid] = hp[perm[j]*64 + c] * tanhv[j];
}

// ---------------- readout: mean/max/sum -> lin1 relu -> lin2 -> log_softmax ----------------
__global__ void k_readout(const float* __restrict__ h3,
                          const float* __restrict__ l1W, const float* __restrict__ l1b,
                          const float* __restrict__ l2W, const float* __restrict__ l2b,
                          float* __restrict__ out) {
    __shared__ float sred[4 * 64], mred[4 * 64];
    __shared__ float gv[192];
    __shared__ float rS[64];
    int g = blockIdx.x, t = threadIdx.x;
    int c = t & 63, grp = t >> 6;
    int base = g * KP_;
    float s = 0.f, m = -1e30f;
    for (int n = grp; n < KP_; n += 4) {
        float v = h3[(base + n)*64 + c];
        s += v; m = fmaxf(m, v);
    }
    sred[t] = s; mred[t] = m;
    __syncthreads();
    if (grp == 0) {
        float ss = sred[c] + sred[64+c] + sred[128+c] + sred[192+c];
        float mm = fmaxf(fmaxf(mred[c], mred[64+c]), fmaxf(mred[128+c], mred[192+c]));
        gv[c]       = ss / (float)KP_;
        gv[64 + c]  = mm;
        gv[128 + c] = ss;
    }
    __syncthreads();
    if (t < 64) {
        float acc = l1b[t];
        for (int k = 0; k < 192; k++) acc += gv[k] * l1W[k*64 + t];
        rS[t] = fmaxf(acc, 0.f);
    }
    __syncthreads();
    if (t == 0) {
        float l0 = l2b[0], l1v = l2b[1];
        for (int hh = 0; hh < 64; hh++) { l0 += rS[hh]*l2W[hh*2+0]; l1v += rS[hh]*l2W[hh*2+1]; }
        float mx  = fmaxf(l0, l1v);
        float lse = mx + logf(expf(l0 - mx) + expf(l1v - mx));
        out[g*2 + 0] = l0  - lse;
        out[g*2 + 1] = l1v - lse;
    }
}

extern "C" void kernel_launch(void* const* d_in, const int* in_sizes, int n_in,
                              void* d_out, int out_size, void* d_ws, size_t ws_size,
                              hipStream_t stream) {
    const float* x      = (const float*)d_in[0];
    const int*   eidx   = (const int*)  d_in[1];
    const float* eattr  = (const float*)d_in[2];
    const float* coords = (const float*)d_in[3];
    const int*   acls   = (const int*)  d_in[4];
    const float* BkT    = (const float*)d_in[5];
    const float* posW   = (const float*)d_in[6];
    const float* posb   = (const float*)d_in[7];
    const float* W1s    = (const float*)d_in[8];
    const float* W1n    = (const float*)d_in[9];
    const float* b1     = (const float*)d_in[10];
    const float* gn1w   = (const float*)d_in[11];
    const float* gn1b   = (const float*)d_in[12];
    const float* gn1ms  = (const float*)d_in[13];
    const float* poolp  = (const float*)d_in[14];
    const float* W2s    = (const float*)d_in[15];
    const float* W2n    = (const float*)d_in[16];
    const float* b2     = (const float*)d_in[17];
    const float* gn2w   = (const float*)d_in[18];
    const float* gn2b   = (const float*)d_in[19];
    const float* gn2ms  = (const float*)d_in[20];
    const float* l1W    = (const float*)d_in[21];
    const float* l1b    = (const float*)d_in[22];
    const float* l2W    = (const float*)d_in[23];
    const float* l2b    = (const float*)d_in[24];

    const int* row  = eidx;
    const int* colp = eidx + ET_;

    float* W = (float*)d_ws;
    const size_t NTH = (size_t)NT_ * 64;
    float* e_buf = W;              // e            (live whole stage 1 + scat2a), then y2
    float* r1    = W + 1*NTH;      // Ae -> hp -> hs2
    float* r2    = W + 2*NTH;      // delta -> delta2 -> h3
    float* r3    = W + 3*NTH;      // hself -> h2 -> agg2
    float* r4    = W + 4*NTH;      // y -> hb -> hp2
    float* r5    = W + 5*NTH;      // agg -> Ae2
    float* small = W + 6*NTH;
    float* deg   = small;                                   // NT floats (reused as deg2)
    float* tanhv = small + NT_;                             // NP2 floats
    int*   perm  = (int*)(small + NT_ + NP2_);              // NP2 ints
    int*   nmap  = (int*)(small + NT_ + 2*NP2_);            // NT ints
    int*   cls2  = (int*)(small + 2*NT_ + 2*NP2_);          // NP2 ints

    // ---- stage 1 ----
    k_e        <<<NT_*64/256, 256, 0, stream>>>(coords, posW, posb, e_buf);
    k_gemm_dual<<<NT_/16,     256, 0, stream>>>(x, FIN_, W1n, W1s, b1, r4 /*y*/, r3 /*hself*/);
    k_scat1    <<<dim3(2, 2, G_), 1024, 0, stream>>>(row, colp, eattr, e_buf, r4 /*y*/,
                                                     r1 /*Ae*/, r5 /*agg*/);
    k_deg1     <<<G_,         256, 0, stream>>>(colp, deg);
    k_bkmv     <<<NT_/4,      256, 0, stream>>>(r1 /*Ae*/, acls, BkT, r2 /*delta*/);
    k_gn       <<<G_,         256, 0, stream>>>(r3 /*hself*/, r5 /*agg*/, deg,
                                                gn1w, gn1b, gn1ms, r2 /*+delta*/,
                                                r4 /*hb*/, N_);
    k_prop     <<<NT_/4,      256, 0, stream>>>(r4 /*hb*/, nullptr, r2 /*delta*/, acls, BkT,
                                                r1 /*hp*/);
    hipMemsetAsync(nmap, 0xFF, NT_ * sizeof(int), stream);
    k_topk     <<<G_,         512, 0, stream>>>(r1 /*hp*/, poolp, acls, perm, tanhv, nmap, cls2);
    k_gather   <<<NP2_*64/256,256, 0, stream>>>(r1 /*hp*/, perm, tanhv, r3 /*h2*/);

    // ---- stage 2 ----
    k_scat2a   <<<dim3(2, G_), 1024, 0, stream>>>(row, colp, nmap, e_buf, r5 /*Ae2*/);
    k_bkmv     <<<NP2_/4,     256, 0, stream>>>(r5 /*Ae2*/, cls2, BkT, r2 /*delta2*/);
    k_prop     <<<NP2_/4,     256, 0, stream>>>(r3 /*h2*/, r2 /*delta2*/, r2 /*delta2*/, cls2, BkT,
                                                r4 /*hp2*/);
    k_gemm_dual<<<NP2_/16,    256, 0, stream>>>(r4 /*hp2*/, 64, W2n, W2s, b2,
                                                e_buf /*y2*/, r1 /*hs2*/);
    k_scat2b   <<<dim3(2, G_), 1024, 0, stream>>>(row, colp, nmap, e_buf /*y2*/, r3 /*agg2*/);
    k_deg2     <<<G_,         256, 0, stream>>>(row, colp, nmap, deg /*deg2*/);
    k_gn       <<<G_,         256, 0, stream>>>(r1 /*hs2*/, r3 /*agg2*/, deg /*deg2*/,
                                                gn2w, gn2b, gn2ms, nullptr,
                                                r2 /*h3*/, KP_);
    k_readout  <<<G_,         256, 0, stream>>>(r2 /*h3*/, l1W, l1b, l2W, l2b, (float*)d_out);
}

// Round 3
// 860.997 us; speedup vs baseline: 2.6112x; 2.6112x over previous
//
#include <hip/hip_runtime.h>
#include <math.h>

#define G_    64
#define N_    512
#define H_    64
#define NT_   32768
#define ET_   1048576
#define EPG_  16384      // edges per graph
#define KP_   359
#define NP2_  22976
#define FIN_  128

// ---------------- transpose Bk_table: BkT[c][d*64+h] = Bk[c][h*64+d] ----------------
__global__ void k_bkT(const float* __restrict__ Bk, float* __restrict__ BkT) {
    int idx = blockIdx.x * 256 + threadIdx.x;          // 6*4096
    int c = idx >> 12, r = idx & 4095;
    int h = r >> 6, d = r & 63;
    BkT[c * 4096 + d * 64 + h] = Bk[c * 4096 + h * 64 + d];
}

// ---------------- per-graph CSR build: histogram + scan + scatter ----------------
// rowCSR entry: (col_global, edge_attr bits). colCSR entry: row_global.
__global__ __launch_bounds__(256)
void k_build(const int* __restrict__ row, const int* __restrict__ col,
             const float* __restrict__ ea,
             int* __restrict__ rowptr, int* __restrict__ colptr,
             int2* __restrict__ rowcsr, int* __restrict__ colcsr,
             float* __restrict__ deg) {
    __shared__ int hr[N_], hc[N_];
    int g = blockIdx.x, t = threadIdx.x;
    for (int i = t; i < N_; i += 256) { hr[i] = 0; hc[i] = 0; }
    __syncthreads();
    int ebase = g * EPG_;
    for (int i = t; i < EPG_; i += 256) {
        atomicAdd(&hr[row[ebase + i] & (N_ - 1)], 1);
        atomicAdd(&hc[col[ebase + i] & (N_ - 1)], 1);
    }
    __syncthreads();
    for (int i = t; i < N_; i += 256) deg[g * N_ + i] = (float)hc[i];
    __syncthreads();
    // exclusive scan of hr (wave 0) and hc (wave 1): each lane handles 8 elems
    int wave = t >> 6, lane = t & 63;
    if (wave < 2) {
        int* h = wave ? hc : hr;
        int base8 = lane * 8;
        int loc[8];
        int tot = 0;
        #pragma unroll
        for (int i = 0; i < 8; i++) { int v = h[base8 + i]; loc[i] = tot; tot += v; }
        int pref = tot;
        for (int off = 1; off < 64; off <<= 1) {
            int u = __shfl_up(pref, off);
            if (lane >= off) pref += u;
        }
        pref -= tot;   // exclusive
        #pragma unroll
        for (int i = 0; i < 8; i++) h[base8 + i] = pref + loc[i];
    }
    __syncthreads();
    for (int i = t; i < N_; i += 256) {
        rowptr[g * N_ + i] = ebase + hr[i];
        colptr[g * N_ + i] = ebase + hc[i];
    }
    if (g == 0 && t == 0) { rowptr[NT_] = ET_; colptr[NT_] = ET_; }
    __syncthreads();
    // scatter (hr/hc now act as cursors, within-graph positions)
    for (int i = t; i < EPG_; i += 256) {
        int rg = row[ebase + i], cg = col[ebase + i];
        float w = ea[ebase + i];
        int pr = atomicAdd(&hr[rg & (N_ - 1)], 1);
        rowcsr[ebase + pr] = make_int2(cg, __float_as_int(w));
        int pc = atomicAdd(&hc[cg & (N_ - 1)], 1);
        colcsr[ebase + pc] = rg;
    }
}

// ---------------- dual GEMM: outA = in@Wa, outB = in@Wb + bias ----------------
__global__ void k_gemm_dual(const float* __restrict__ in, int K,
                            const float* __restrict__ Wa, const float* __restrict__ Wb,
                            const float* __restrict__ bias,
                            float* __restrict__ outA, float* __restrict__ outB) {
    __shared__ float inT[16 * FIN_];
    int row0 = blockIdx.x * 16;
    int t = threadIdx.x;
    for (int idx = t; idx < 16 * K; idx += 256) inT[idx] = in[row0 * K + idx];
    __syncthreads();
    int c = t & 63, rb = t >> 6;
    for (int rr = 0; rr < 4; rr++) {
        int r = rb * 4 + rr;
        float accA = 0.f, accB = bias[c];
        const float* ip = inT + r * K;
        for (int k = 0; k < K; k++) {
            float a = ip[k];
            accA += a * Wa[k*64 + c];
            accB += a * Wb[k*64 + c];
        }
        outA[(row0 + r)*64 + c] = accA;
        outB[(row0 + r)*64 + c] = accB;
    }
}

// ---------------- stage-1 Ae gather: Ae[n,ch] = sum_{row=n} w * e[col,ch]
// e recomputed on the fly: e[col,ch] = coords[col]·posW[:,ch] + posb[ch]
__global__ __launch_bounds__(256)
void k_gaeA(const int* __restrict__ rowptr, const int2* __restrict__ rcsr,
            const float* __restrict__ coords,
            const float* __restrict__ posW, const float* __restrict__ posb,
            float* __restrict__ Ae) {
    int node = blockIdx.x * 4 + (threadIdx.x >> 6);
    int lane = threadIdx.x & 63;
    float w0 = posW[0*64 + lane], w1 = posW[1*64 + lane], w2 = posW[2*64 + lane];
    float pb = posb[lane];
    int start = rowptr[node], end = rowptr[node + 1];
    float acc = 0.f;
    #pragma unroll 4
    for (int k = start; k < end; k++) {
        int2 ent = rcsr[k];
        int c = ent.x;
        float w = __int_as_float(ent.y);
        float e = pb + coords[c*3+0]*w0 + coords[c*3+1]*w1 + coords[c*3+2]*w2;
        acc += w * e;
    }
    Ae[node*64 + lane] = acc;
}

// ---------------- stage-1 agg gather: agg[n,ch] = sum_{col=n} y[row,ch] ----------------
__global__ __launch_bounds__(256)
void k_gagg(const int* __restrict__ colptr, const int* __restrict__ ccsr,
            const float* __restrict__ y, float* __restrict__ agg) {
    int node = blockIdx.x * 4 + (threadIdx.x >> 6);
    int lane = threadIdx.x & 63;
    int start = colptr[node], end = colptr[node + 1];
    float acc = 0.f;
    #pragma unroll 4
    for (int k = start; k < end; k++) {
        int r = ccsr[k];
        acc += y[r*64 + lane];
    }
    agg[node*64 + lane] = acc;
}

// ---------------- per-node matvec via BkT: out[n,h] = sum_d Bk[h,d]*in[n,d] ----------------
__global__ __launch_bounds__(256)
void k_bkmv2(const float* __restrict__ in, const int* __restrict__ cls,
             const float* __restrict__ BkT, float* __restrict__ out) {
    int node = blockIdx.x * 4 + (threadIdx.x >> 6);
    int lane = threadIdx.x & 63;
    const float* B  = BkT + cls[node] * 4096;   // [d*64 + h]
    const float* iv = in + node * 64;
    float acc = 0.f;
    #pragma unroll 8
    for (int d = 0; d < 64; d++) acc += B[d*64 + lane] * iv[d];
    out[node*64 + lane] = acc;
}

// ---------------- propagate: h=(inA+inB); out[n,i]=sum_j Bk[i,j]h_j + delta[n,i]*sum_j h_j
__global__ __launch_bounds__(256)
void k_prop2(const float* __restrict__ inA, const float* __restrict__ inB,
             const float* __restrict__ delta, const int* __restrict__ cls,
             const float* __restrict__ BkT, float* __restrict__ out) {
    int node = blockIdx.x * 4 + (threadIdx.x >> 6);
    int lane = threadIdx.x & 63;
    const float* B  = BkT + cls[node] * 4096;   // [j*64 + i]
    const float* a  = inA + node * 64;
    const float* b  = inB ? inB + node * 64 : nullptr;
    float acc = 0.f, s = 0.f;
    #pragma unroll 8
    for (int j = 0; j < 64; j++) {
        float hj = a[j] + (b ? b[j] : 0.f);     // broadcast loads, L1-hot
        s   += hj;
        acc += B[j*64 + lane] * hj;
    }
    out[node*64 + lane] = acc + delta[node*64 + lane] * s;
}

// ---------------- graph_norm + elu (+ optional delta add) ----------------
__global__ void k_gn(const float* __restrict__ hself, const float* __restrict__ agg,
                     const float* __restrict__ deg,
                     const float* __restrict__ w, const float* __restrict__ b,
                     const float* __restrict__ ms,
                     const float* __restrict__ delta,   // nullable
                     float* __restrict__ out, int NPG) {
    __shared__ float red[4 * 64];
    __shared__ float meanS[64], istdS[64];
    int g = blockIdx.x, t = threadIdx.x;
    int c = t & 63, grp = t >> 6;
    int base = g * NPG;
    float s = 0.f;
    for (int n = grp; n < NPG; n += 4) {
        int node = base + n;
        s += hself[node*64 + c] + agg[node*64 + c] / fmaxf(deg[node], 1.0f);
    }
    red[t] = s;
    __syncthreads();
    if (grp == 0) meanS[c] = (red[c] + red[64+c] + red[128+c] + red[192+c]) / (float)NPG;
    __syncthreads();
    float mval = meanS[c] * ms[c];
    s = 0.f;
    for (int n = grp; n < NPG; n += 4) {
        int node = base + n;
        float v = hself[node*64 + c] + agg[node*64 + c] / fmaxf(deg[node], 1.0f) - mval;
        s += v * v;
    }
    red[t] = s;
    __syncthreads();
    if (grp == 0) {
        float var = (red[c] + red[64+c] + red[128+c] + red[192+c]) / (float)NPG;
        istdS[c] = rsqrtf(var + 1e-5f);
    }
    __syncthreads();
    float wv = w[c], bv = b[c], istd = istdS[c];
    for (int n = grp; n < NPG; n += 4) {
        int node = base + n;
        float v = hself[node*64 + c] + agg[node*64 + c] / fmaxf(deg[node], 1.0f) - mval;
        v = wv * v * istd + bv;
        v = v > 0.f ? v : expm1f(v);
        if (delta) v += delta[node*64 + c];
        out[node*64 + c] = v;
    }
}

// ---------------- top-k per graph (desc score, ties by lower idx) ----------------
__global__ void k_topk(const float* __restrict__ hp, const float* __restrict__ p,
                       const int* __restrict__ cls,
                       int* __restrict__ perm, float* __restrict__ tanhv,
                       int* __restrict__ node_map, int* __restrict__ class2) {
    __shared__ float key[N_];
    __shared__ int   idxS[N_];
    __shared__ float pS[64];
    __shared__ float nrm;
    int g = blockIdx.x, t = threadIdx.x;
    if (t < 64) pS[t] = p[t];
    __syncthreads();
    if (t == 0) {
        float s = 0.f;
        for (int i = 0; i < 64; i++) s += pS[i] * pS[i];
        nrm = sqrtf(s);
    }
    __syncthreads();
    {
        float acc = 0.f;
        const float* hv = hp + (size_t)(g*N_ + t) * 64;
        for (int cdx = 0; cdx < 64; cdx++) acc += hv[cdx] * pS[cdx];
        key[t]  = acc / nrm;
        idxS[t] = t;
    }
    __syncthreads();
    for (int k = 2; k <= N_; k <<= 1) {
        for (int j = k >> 1; j > 0; j >>= 1) {
            int i = t, ixj = i ^ j;
            if (ixj > i) {
                float ki = key[i], kj = key[ixj];
                int   ii = idxS[i], ij = idxS[ixj];
                bool before = (ki > kj) || (ki == kj && ii < ij);
                bool dir = ((i & k) == 0);
                if (dir ? !before : before) {
                    key[i] = kj; key[ixj] = ki;
                    idxS[i] = ij; idxS[ixj] = ii;
                }
            }
            __syncthreads();
        }
    }
    if (t < KP_) {
        int orig  = idxS[t];
        int gnode = g * N_ + orig;
        int pj    = g * KP_ + t;
        perm[pj]     = gnode;
        tanhv[pj]    = tanhf(key[t]);
        node_map[gnode] = pj;
        class2[pj]   = cls[gnode];
    }
}

// ---------------- pooled gather: h2[j] = hp[perm[j]] * tanhv[j] ----------------
__global__ void k_gather(const float* __restrict__ hp, const int* __restrict__ perm,
                         const float* __restrict__ tanhv, float* __restrict__ h2) {
    int gid = blockIdx.x * 256 + threadIdx.x;   // NP2*64
    int j = gid >> 6, c = gid & 63;
    h2[gid] = hp[perm[j]*64 + c] * tanhv[j];
}

// ---------------- stage-2 Ae2 gather: Ae2[j,ch] = sum_{row=perm[j], nmap[col]>=0} e[col,ch]
__global__ __launch_bounds__(256)
void k_gae2(const int* __restrict__ rowptr, const int2* __restrict__ rcsr,
            const int* __restrict__ perm, const int* __restrict__ nmap,
            const float* __restrict__ coords,
            const float* __restrict__ posW, const float* __restrict__ posb,
            float* __restrict__ Ae2) {
    int j = blockIdx.x * 4 + (threadIdx.x >> 6);
    int lane = threadIdx.x & 63;
    float w0 = posW[0*64 + lane], w1 = posW[1*64 + lane], w2 = posW[2*64 + lane];
    float pb = posb[lane];
    int orig = perm[j];
    int start = rowptr[orig], end = rowptr[orig + 1];
    float acc = 0.f;
    #pragma unroll 4
    for (int k = start; k < end; k++) {
        int2 ent = rcsr[k];
        int c = ent.x;
        if (nmap[c] >= 0) {
            acc += pb + coords[c*3+0]*w0 + coords[c*3+1]*w1 + coords[c*3+2]*w2;
        }
    }
    Ae2[j*64 + lane] = acc;
}

// ---------------- stage-2 agg gather + deg2: agg2[j,ch] = sum_{col=perm[j], s2>=0} y2[s2,ch]
__global__ __launch_bounds__(256)
void k_gagg2(const int* __restrict__ colptr, const int* __restrict__ ccsr,
             const int* __restrict__ perm, const int* __restrict__ nmap,
             const float* __restrict__ y2,
             float* __restrict__ agg2, float* __restrict__ deg2) {
    int j = blockIdx.x * 4 + (threadIdx.x >> 6);
    int lane = threadIdx.x & 63;
    int orig = perm[j];
    int start = colptr[orig], end = colptr[orig + 1];
    float acc = 0.f;
    int cnt = 0;
    #pragma unroll 4
    for (int k = start; k < end; k++) {
        int s2 = nmap[ccsr[k]];
        if (s2 >= 0) {
            acc += y2[s2*64 + lane];
            cnt++;
        }
    }
    agg2[j*64 + lane] = acc;
    if (lane == 0) deg2[j] = (float)cnt;
}

// ---------------- readout ----------------
__global__ void k_readout(const float* __restrict__ h3,
                          const float* __restrict__ l1W, const float* __restrict__ l1b,
                          const float* __restrict__ l2W, const float* __restrict__ l2b,
                          float* __restrict__ out) {
    __shared__ float sred[4 * 64], mred[4 * 64];
    __shared__ float gv[192];
    __shared__ float rS[64];
    int g = blockIdx.x, t = threadIdx.x;
    int c = t & 63, grp = t >> 6;
    int base = g * KP_;
    float s = 0.f, m = -1e30f;
    for (int n = grp; n < KP_; n += 4) {
        float v = h3[(base + n)*64 + c];
        s += v; m = fmaxf(m, v);
    }
    sred[t] = s; mred[t] = m;
    __syncthreads();
    if (grp == 0) {
        float ss = sred[c] + sred[64+c] + sred[128+c] + sred[192+c];
        float mm = fmaxf(fmaxf(mred[c], mred[64+c]), fmaxf(mred[128+c], mred[192+c]));
        gv[c]       = ss / (float)KP_;
        gv[64 + c]  = mm;
        gv[128 + c] = ss;
    }
    __syncthreads();
    if (t < 64) {
        float acc = l1b[t];
        for (int k = 0; k < 192; k++) acc += gv[k] * l1W[k*64 + t];
        rS[t] = fmaxf(acc, 0.f);
    }
    __syncthreads();
    if (t == 0) {
        float l0 = l2b[0], l1v = l2b[1];
        for (int hh = 0; hh < 64; hh++) { l0 += rS[hh]*l2W[hh*2+0]; l1v += rS[hh]*l2W[hh*2+1]; }
        float mx  = fmaxf(l0, l1v);
        float lse = mx + logf(expf(l0 - mx) + expf(l1v - mx));
        out[g*2 + 0] = l0  - lse;
        out[g*2 + 1] = l1v - lse;
    }
}

extern "C" void kernel_launch(void* const* d_in, const int* in_sizes, int n_in,
                              void* d_out, int out_size, void* d_ws, size_t ws_size,
                              hipStream_t stream) {
    const float* x      = (const float*)d_in[0];
    const int*   eidx   = (const int*)  d_in[1];
    const float* eattr  = (const float*)d_in[2];
    const float* coords = (const float*)d_in[3];
    const int*   acls   = (const int*)  d_in[4];
    const float* BkTab  = (const float*)d_in[5];
    const float* posW   = (const float*)d_in[6];
    const float* posb   = (const float*)d_in[7];
    const float* W1s    = (const float*)d_in[8];
    const float* W1n    = (const float*)d_in[9];
    const float* b1     = (const float*)d_in[10];
    const float* gn1w   = (const float*)d_in[11];
    const float* gn1b   = (const float*)d_in[12];
    const float* gn1ms  = (const float*)d_in[13];
    const float* poolp  = (const float*)d_in[14];
    const float* W2s    = (const float*)d_in[15];
    const float* W2n    = (const float*)d_in[16];
    const float* b2     = (const float*)d_in[17];
    const float* gn2w   = (const float*)d_in[18];
    const float* gn2b   = (const float*)d_in[19];
    const float* gn2ms  = (const float*)d_in[20];
    const float* l1W    = (const float*)d_in[21];
    const float* l1b    = (const float*)d_in[22];
    const float* l2W    = (const float*)d_in[23];
    const float* l2b    = (const float*)d_in[24];

    const int* row  = eidx;
    const int* colp = eidx + ET_;

    float* W = (float*)d_ws;
    const size_t NTH = (size_t)NT_ * 64;        // 2,097,152 floats
    float* b0 = W;                              // y -> hb -> h2 -> agg2
    float* b1buf = W + 1*NTH;                   // hself -> hp -> hp2 -> h3
    float* b2buf = W + 2*NTH;                   // Ae -> agg -> Ae2 -> y2
    float* b3buf = W + 3*NTH;                   // delta -> delta2 -> hs2
    float* p = W + 4*NTH;
    int2*  rowcsr = (int2*)p;        p += 2*(size_t)ET_;   // 8 MB
    int*   colcsr = (int*)p;         p += ET_;             // 4 MB
    int*   rowptr = (int*)p;         p += NT_ + 8;
    int*   colptr = (int*)p;         p += NT_ + 8;
    float* deg    = p;               p += NT_;             // stage-1 deg
    float* deg2   = p;               p += NP2_;
    float* tanhv  = p;               p += NP2_;
    int*   perm   = (int*)p;         p += NP2_;
    int*   nmap   = (int*)p;         p += NT_;
    int*   cls2   = (int*)p;         p += NP2_;
    float* BkT    = p;               p += 6 * 4096;

    // ---- prep ----
    k_bkT      <<<96,   256, 0, stream>>>(BkTab, BkT);
    k_build    <<<G_,   256, 0, stream>>>(row, colp, eattr, rowptr, colptr,
                                          rowcsr, colcsr, deg);
    hipMemsetAsync(nmap, 0xFF, NT_ * sizeof(int), stream);

    // ---- stage 1 ----
    k_gemm_dual<<<NT_/16,  256, 0, stream>>>(x, FIN_, W1n, W1s, b1,
                                             b0 /*y*/, b1buf /*hself*/);
    k_gaeA     <<<NT_/4,   256, 0, stream>>>(rowptr, rowcsr, coords, posW, posb,
                                             b2buf /*Ae*/);
    k_bkmv2    <<<NT_/4,   256, 0, stream>>>(b2buf /*Ae*/, acls, BkT, b3buf /*delta*/);
    k_gagg     <<<NT_/4,   256, 0, stream>>>(colptr, colcsr, b0 /*y*/, b2buf /*agg*/);
    k_gn       <<<G_,      256, 0, stream>>>(b1buf /*hself*/, b2buf /*agg*/, deg,
                                             gn1w, gn1b, gn1ms, b3buf /*+delta*/,
                                             b0 /*hb*/, N_);
    k_prop2    <<<NT_/4,   256, 0, stream>>>(b0 /*hb*/, nullptr, b3buf /*delta*/, acls, BkT,
                                             b1buf /*hp*/);
    k_topk     <<<G_,      512, 0, stream>>>(b1buf /*hp*/, poolp, acls,
                                             perm, tanhv, nmap, cls2);
    k_gather   <<<NP2_*64/256, 256, 0, stream>>>(b1buf /*hp*/, perm, tanhv, b0 /*h2*/);

    // ---- stage 2 ----
    k_gae2     <<<NP2_/4,  256, 0, stream>>>(rowptr, rowcsr, perm, nmap,
                                             coords, posW, posb, b2buf /*Ae2*/);
    k_bkmv2    <<<NP2_/4,  256, 0, stream>>>(b2buf /*Ae2*/, cls2, BkT, b3buf /*delta2*/);
    k_prop2    <<<NP2_/4,  256, 0, stream>>>(b0 /*h2*/, b3buf /*delta2*/, b3buf /*delta2*/,
                                             cls2, BkT, b1buf /*hp2*/);
    k_gemm_dual<<<NP2_/16, 256, 0, stream>>>(b1buf /*hp2*/, 64, W2n, W2s, b2,
                                             b2buf /*y2*/, b3buf /*hs2*/);
    k_gagg2    <<<NP2_/4,  256, 0, stream>>>(colptr, colcsr, perm, nmap,
                                             b2buf /*y2*/, b0 /*agg2*/, deg2);
    k_gn       <<<G_,      256, 0, stream>>>(b3buf /*hs2*/, b0 /*agg2*/, deg2,
                                             gn2w, gn2b, gn2ms, nullptr,
                                             b1buf /*h3*/, KP_);
    k_readout  <<<G_,      256, 0, stream>>>(b1buf /*h3*/, l1W, l1b, l2W, l2b,
                                             (float*)d_out);
}

// Round 4
// 659.017 us; speedup vs baseline: 3.4115x; 1.3065x over previous
//
#include <hip/hip_runtime.h>
#include <math.h>

#define G_    64
#define N_    512
#define H_    64
#define NT_   32768
#define ET_   1048576
#define EPG_  16384      // edges per graph
#define KP_   359
#define NP2_  22976
#define FIN_  128

// ---------------- transpose Bk_table: BkT[c][d*64+h] = Bk[c][h*64+d] ----------------
__global__ void k_bkT(const float* __restrict__ Bk, float* __restrict__ BkT) {
    int idx = blockIdx.x * 256 + threadIdx.x;          // 6*4096
    int c = idx >> 12, r = idx & 4095;
    int h = r >> 6, d = r & 63;
    BkT[c * 4096 + d * 64 + h] = Bk[c * 4096 + h * 64 + d];
}

// ---------------- per-graph CSR build: histogram + scan + scatter ----------------
__global__ __launch_bounds__(256)
void k_build(const int* __restrict__ row, const int* __restrict__ col,
             const float* __restrict__ ea,
             int* __restrict__ rowptr, int* __restrict__ colptr,
             int2* __restrict__ rowcsr, int* __restrict__ colcsr,
             float* __restrict__ deg) {
    __shared__ int hr[N_], hc[N_];
    int g = blockIdx.x, t = threadIdx.x;
    for (int i = t; i < N_; i += 256) { hr[i] = 0; hc[i] = 0; }
    __syncthreads();
    int ebase = g * EPG_;
    for (int i = t; i < EPG_; i += 256) {
        atomicAdd(&hr[row[ebase + i] & (N_ - 1)], 1);
        atomicAdd(&hc[col[ebase + i] & (N_ - 1)], 1);
    }
    __syncthreads();
    for (int i = t; i < N_; i += 256) deg[g * N_ + i] = (float)hc[i];
    __syncthreads();
    int wave = t >> 6, lane = t & 63;
    if (wave < 2) {
        int* h = wave ? hc : hr;
        int base8 = lane * 8;
        int loc[8];
        int tot = 0;
        #pragma unroll
        for (int i = 0; i < 8; i++) { int v = h[base8 + i]; loc[i] = tot; tot += v; }
        int pref = tot;
        for (int off = 1; off < 64; off <<= 1) {
            int u = __shfl_up(pref, off);
            if (lane >= off) pref += u;
        }
        pref -= tot;   // exclusive
        #pragma unroll
        for (int i = 0; i < 8; i++) h[base8 + i] = pref + loc[i];
    }
    __syncthreads();
    for (int i = t; i < N_; i += 256) {
        rowptr[g * N_ + i] = ebase + hr[i];
        colptr[g * N_ + i] = ebase + hc[i];
    }
    if (g == 0 && t == 0) { rowptr[NT_] = ET_; colptr[NT_] = ET_; }
    __syncthreads();
    for (int i = t; i < EPG_; i += 256) {
        int rg = row[ebase + i], cg = col[ebase + i];
        float w = ea[ebase + i];
        int pr = atomicAdd(&hr[rg & (N_ - 1)], 1);
        rowcsr[ebase + pr] = make_int2(cg, __float_as_int(w));
        int pc = atomicAdd(&hc[cg & (N_ - 1)], 1);
        colcsr[ebase + pc] = rg;
    }
}

// ---------------- dual GEMM: outA = in@Wa, outB = in@Wb + bias ----------------
__global__ void k_gemm_dual(const float* __restrict__ in, int K,
                            const float* __restrict__ Wa, const float* __restrict__ Wb,
                            const float* __restrict__ bias,
                            float* __restrict__ outA, float* __restrict__ outB) {
    __shared__ float inT[16 * FIN_];
    int row0 = blockIdx.x * 16;
    int t = threadIdx.x;
    for (int idx = t; idx < 16 * K; idx += 256) inT[idx] = in[row0 * K + idx];
    __syncthreads();
    int c = t & 63, rb = t >> 6;
    for (int rr = 0; rr < 4; rr++) {
        int r = rb * 4 + rr;
        float accA = 0.f, accB = bias[c];
        const float* ip = inT + r * K;
        for (int k = 0; k < K; k++) {
            float a = ip[k];
            accA += a * Wa[k*64 + c];
            accB += a * Wb[k*64 + c];
        }
        outA[(row0 + r)*64 + c] = accA;
        outB[(row0 + r)*64 + c] = accB;
    }
}

// ---------------- stage-1 Ae gather (e recomputed on the fly) ----------------
__global__ __launch_bounds__(256)
void k_gaeA(const int* __restrict__ rowptr, const int2* __restrict__ rcsr,
            const float* __restrict__ coords,
            const float* __restrict__ posW, const float* __restrict__ posb,
            float* __restrict__ Ae) {
    int node = blockIdx.x * 4 + (threadIdx.x >> 6);
    int lane = threadIdx.x & 63;
    float w0 = posW[0*64 + lane], w1 = posW[1*64 + lane], w2 = posW[2*64 + lane];
    float pb = posb[lane];
    int start = rowptr[node], end = rowptr[node + 1];
    float acc = 0.f;
    #pragma unroll 4
    for (int k = start; k < end; k++) {
        int2 ent = rcsr[k];
        int c = ent.x;
        float w = __int_as_float(ent.y);
        float e = pb + coords[c*3+0]*w0 + coords[c*3+1]*w1 + coords[c*3+2]*w2;
        acc += w * e;
    }
    Ae[node*64 + lane] = acc;
}

// ---------------- stage-1 agg gather ----------------
__global__ __launch_bounds__(256)
void k_gagg(const int* __restrict__ colptr, const int* __restrict__ ccsr,
            const float* __restrict__ y, float* __restrict__ agg) {
    int node = blockIdx.x * 4 + (threadIdx.x >> 6);
    int lane = threadIdx.x & 63;
    int start = colptr[node], end = colptr[node + 1];
    float acc = 0.f;
    #pragma unroll 4
    for (int k = start; k < end; k++) {
        int r = ccsr[k];
        acc += y[r*64 + lane];
    }
    agg[node*64 + lane] = acc;
}

// ---------------- per-node matvec via BkT ----------------
__global__ __launch_bounds__(256)
void k_bkmv2(const float* __restrict__ in, const int* __restrict__ cls,
             const float* __restrict__ BkT, float* __restrict__ out) {
    int node = blockIdx.x * 4 + (threadIdx.x >> 6);
    int lane = threadIdx.x & 63;
    const float* B  = BkT + cls[node] * 4096;   // [d*64 + h]
    const float* iv = in + node * 64;
    float acc = 0.f;
    #pragma unroll 8
    for (int d = 0; d < 64; d++) acc += B[d*64 + lane] * iv[d];
    out[node*64 + lane] = acc;
}

// ---------------- stage-2 propagate ----------------
__global__ __launch_bounds__(256)
void k_prop2(const float* __restrict__ inA, const float* __restrict__ inB,
             const float* __restrict__ delta, const int* __restrict__ cls,
             const float* __restrict__ BkT, float* __restrict__ out) {
    int node = blockIdx.x * 4 + (threadIdx.x >> 6);
    int lane = threadIdx.x & 63;
    const float* B  = BkT + cls[node] * 4096;
    const float* a  = inA + node * 64;
    const float* b  = inB ? inB + node * 64 : nullptr;
    float acc = 0.f, s = 0.f;
    #pragma unroll 8
    for (int j = 0; j < 64; j++) {
        float hj = a[j] + (b ? b[j] : 0.f);
        s   += hj;
        acc += B[j*64 + lane] * hj;
    }
    out[node*64 + lane] = acc + delta[node*64 + lane] * s;
}

// ---------------- graph_norm stats: one-pass sum & sumsq partials ----------------
__global__ __launch_bounds__(256)
void k_gnstat(const float* __restrict__ hs, const float* __restrict__ agg,
              const float* __restrict__ deg, float* __restrict__ partial,
              int NPG, int CH, int npc) {
    __shared__ float r1[256], r2[256];
    int b = blockIdx.x;
    int g = b / CH, chunk = b % CH;
    int t = threadIdx.x, c = t & 63, grp = t >> 6;
    int n0 = chunk * npc;
    int nend = min(n0 + npc, NPG);
    float s1 = 0.f, s2 = 0.f;
    for (int n = n0 + grp; n < nend; n += 4) {
        int node = g * NPG + n;
        float v = hs[node*64 + c] + agg[node*64 + c] / fmaxf(deg[node], 1.f);
        s1 += v; s2 += v * v;
    }
    r1[t] = s1; r2[t] = s2;
    __syncthreads();
    if (grp == 0) {
        partial[b*128 + c]      = r1[c] + r1[64+c] + r1[128+c] + r1[192+c];
        partial[b*128 + 64 + c] = r2[c] + r2[64+c] + r2[128+c] + r2[192+c];
    }
}

// ---------------- graph_norm finalize: mval = ms*mean, istd ----------------
__global__ void k_gnfin(const float* __restrict__ partial, const float* __restrict__ ms,
                        int CH, int NPG,
                        float* __restrict__ mval, float* __restrict__ istdv) {
    int g = blockIdx.x, t = threadIdx.x;   // 64 threads
    float s1 = 0.f, s2 = 0.f;
    for (int i = 0; i < CH; i++) {
        s1 += partial[(g*CH + i)*128 + t];
        s2 += partial[(g*CH + i)*128 + 64 + t];
    }
    float m = s1 / (float)NPG, q = s2 / (float)NPG, msv = ms[t];
    float var = q - msv * m * m * (2.f - msv);   // E[(h-ms*m)^2]
    mval[g*64 + t]  = msv * m;
    istdv[g*64 + t] = rsqrtf(var + 1e-5f);
}

// ---------------- stage-1 fused: gn-apply + elu + (+delta) + propagate ----------------
__global__ __launch_bounds__(256)
void k_gnprop(const float* __restrict__ hself, const float* __restrict__ agg,
              const float* __restrict__ deg,
              const float* __restrict__ mval, const float* __restrict__ istdv,
              const float* __restrict__ w, const float* __restrict__ b,
              const float* __restrict__ delta, const int* __restrict__ cls,
              const float* __restrict__ BkT, float* __restrict__ out) {
    __shared__ float hT[256];
    int t = threadIdx.x;
    int node = blockIdx.x * 4 + (t >> 6);
    int lane = t & 63;
    int g = node >> 9;                       // N_=512 nodes/graph
    float v = hself[node*64 + lane] + agg[node*64 + lane] / fmaxf(deg[node], 1.f);
    v = w[lane] * (v - mval[g*64 + lane]) * istdv[g*64 + lane] + b[lane];
    v = v > 0.f ? v : expm1f(v);
    float d = delta[node*64 + lane];
    v += d;
    hT[t] = v;
    __syncthreads();
    float s = v;
    #pragma unroll
    for (int off = 32; off; off >>= 1) s += __shfl_down(s, off);
    s = __shfl(s, 0);
    const float* B  = BkT + cls[node] * 4096;
    const float* hv = hT + (t & ~63);
    float acc = 0.f;
    #pragma unroll 8
    for (int j = 0; j < 64; j++) acc += B[j*64 + lane] * hv[j];
    out[node*64 + lane] = acc + d * s;
}

// ---------------- stage-2 gn apply + elu ----------------
__global__ void k_gnapply(const float* __restrict__ hs, const float* __restrict__ agg,
                          const float* __restrict__ deg,
                          const float* __restrict__ mval, const float* __restrict__ istdv,
                          const float* __restrict__ w, const float* __restrict__ b,
                          float* __restrict__ out) {
    int gid = blockIdx.x * 256 + threadIdx.x;    // NP2*64
    int j = gid >> 6, lane = gid & 63;
    int g = j / KP_;
    float v = hs[gid] + agg[gid] / fmaxf(deg[j], 1.f);
    v = w[lane] * (v - mval[g*64 + lane]) * istdv[g*64 + lane] + b[lane];
    out[gid] = v > 0.f ? v : expm1f(v);
}

// ---------------- top-k per graph (desc score, ties by lower idx) ----------------
__global__ void k_topk(const float* __restrict__ hp, const float* __restrict__ p,
                       const int* __restrict__ cls,
                       int* __restrict__ perm, float* __restrict__ tanhv,
                       int* __restrict__ node_map, int* __restrict__ class2) {
    __shared__ float key[N_];
    __shared__ int   idxS[N_];
    __shared__ float pS[64];
    __shared__ float nrm;
    int g = blockIdx.x, t = threadIdx.x;
    if (t < 64) pS[t] = p[t];
    __syncthreads();
    if (t == 0) {
        float s = 0.f;
        for (int i = 0; i < 64; i++) s += pS[i] * pS[i];
        nrm = sqrtf(s);
    }
    __syncthreads();
    {
        float acc = 0.f;
        const float* hv = hp + (size_t)(g*N_ + t) * 64;
        for (int cdx = 0; cdx < 64; cdx++) acc += hv[cdx] * pS[cdx];
        key[t]  = acc / nrm;
        idxS[t] = t;
    }
    __syncthreads();
    for (int k = 2; k <= N_; k <<= 1) {
        for (int j = k >> 1; j > 0; j >>= 1) {
            int i = t, ixj = i ^ j;
            if (ixj > i) {
                float ki = key[i], kj = key[ixj];
                int   ii = idxS[i], ij = idxS[ixj];
                bool before = (ki > kj) || (ki == kj && ii < ij);
                bool dir = ((i & k) == 0);
                if (dir ? !before : before) {
                    key[i] = kj; key[ixj] = ki;
                    idxS[i] = ij; idxS[ixj] = ii;
                }
            }
            __syncthreads();
        }
    }
    if (t < KP_) {
        int orig  = idxS[t];
        int gnode = g * N_ + orig;
        int pj    = g * KP_ + t;
        perm[pj]     = gnode;
        tanhv[pj]    = tanhf(key[t]);
        node_map[gnode] = pj;
        class2[pj]   = cls[gnode];
    }
}

// ---------------- pooled gather: h2[j] = hp[perm[j]] * tanhv[j] ----------------
__global__ void k_gather(const float* __restrict__ hp, const int* __restrict__ perm,
                         const float* __restrict__ tanhv, float* __restrict__ h2) {
    int gid = blockIdx.x * 256 + threadIdx.x;   // NP2*64
    int j = gid >> 6, c = gid & 63;
    h2[gid] = hp[perm[j]*64 + c] * tanhv[j];
}

// ---------------- stage-2 Ae2 gather ----------------
__global__ __launch_bounds__(256)
void k_gae2(const int* __restrict__ rowptr, const int2* __restrict__ rcsr,
            const int* __restrict__ perm, const int* __restrict__ nmap,
            const float* __restrict__ coords,
            const float* __restrict__ posW, const float* __restrict__ posb,
            float* __restrict__ Ae2) {
    int j = blockIdx.x * 4 + (threadIdx.x >> 6);
    int lane = threadIdx.x & 63;
    float w0 = posW[0*64 + lane], w1 = posW[1*64 + lane], w2 = posW[2*64 + lane];
    float pb = posb[lane];
    int orig = perm[j];
    int start = rowptr[orig], end = rowptr[orig + 1];
    float acc = 0.f;
    #pragma unroll 4
    for (int k = start; k < end; k++) {
        int2 ent = rcsr[k];
        int c = ent.x;
        if (nmap[c] >= 0) {
            acc += pb + coords[c*3+0]*w0 + coords[c*3+1]*w1 + coords[c*3+2]*w2;
        }
    }
    Ae2[j*64 + lane] = acc;
}

// ---------------- stage-2 agg gather + deg2 ----------------
__global__ __launch_bounds__(256)
void k_gagg2(const int* __restrict__ colptr, const int* __restrict__ ccsr,
             const int* __restrict__ perm, const int* __restrict__ nmap,
             const float* __restrict__ y2,
             float* __restrict__ agg2, float* __restrict__ deg2) {
    int j = blockIdx.x * 4 + (threadIdx.x >> 6);
    int lane = threadIdx.x & 63;
    int orig = perm[j];
    int start = colptr[orig], end = colptr[orig + 1];
    float acc = 0.f;
    int cnt = 0;
    #pragma unroll 4
    for (int k = start; k < end; k++) {
        int s2 = nmap[ccsr[k]];
        if (s2 >= 0) {
            acc += y2[s2*64 + lane];
            cnt++;
        }
    }
    agg2[j*64 + lane] = acc;
    if (lane == 0) deg2[j] = (float)cnt;
}

// ---------------- readout partials: sum & max per (graph, chunk, channel) ----------------
__global__ __launch_bounds__(256)
void k_rpart(const float* __restrict__ h3, float* __restrict__ part,
             int CH, int npc) {
    __shared__ float r1[256], r2[256];
    int b = blockIdx.x;
    int g = b / CH, chunk = b % CH;
    int t = threadIdx.x, c = t & 63, grp = t >> 6;
    int n0 = chunk * npc, nend = min(n0 + npc, KP_);
    float s = 0.f, m = -1e30f;
    for (int n = n0 + grp; n < nend; n += 4) {
        float v = h3[(g*KP_ + n)*64 + c];
        s += v; m = fmaxf(m, v);
    }
    r1[t] = s; r2[t] = m;
    __syncthreads();
    if (grp == 0) {
        part[b*128 + c]      = r1[c] + r1[64+c] + r1[128+c] + r1[192+c];
        part[b*128 + 64 + c] = fmaxf(fmaxf(r2[c], r2[64+c]), fmaxf(r2[128+c], r2[192+c]));
    }
}

// ---------------- readout finalize: lin1 relu -> lin2 -> log_softmax ----------------
__global__ void k_rfin(const float* __restrict__ part, int CH,
                       const float* __restrict__ l1W, const float* __restrict__ l1b,
                       const float* __restrict__ l2W, const float* __restrict__ l2b,
                       float* __restrict__ out) {
    __shared__ float gv[192], rS[64];
    int g = blockIdx.x, t = threadIdx.x;   // 64 threads
    float s = 0.f, m = -1e30f;
    for (int i = 0; i < CH; i++) {
        s += part[(g*CH + i)*128 + t];
        m = fmaxf(m, part[(g*CH + i)*128 + 64 + t]);
    }
    gv[t] = s / (float)KP_;
    gv[64 + t] = m;
    gv[128 + t] = s;
    __syncthreads();
    float acc = l1b[t];
    for (int k = 0; k < 192; k++) acc += gv[k] * l1W[k*64 + t];
    rS[t] = fmaxf(acc, 0.f);
    __syncthreads();
    if (t == 0) {
        float l0 = l2b[0], l1v = l2b[1];
        for (int hh = 0; hh < 64; hh++) { l0 += rS[hh]*l2W[hh*2+0]; l1v += rS[hh]*l2W[hh*2+1]; }
        float mx  = fmaxf(l0, l1v);
        float lse = mx + logf(expf(l0 - mx) + expf(l1v - mx));
        out[g*2 + 0] = l0  - lse;
        out[g*2 + 1] = l1v - lse;
    }
}

extern "C" void kernel_launch(void* const* d_in, const int* in_sizes, int n_in,
                              void* d_out, int out_size, void* d_ws, size_t ws_size,
                              hipStream_t stream) {
    const float* x      = (const float*)d_in[0];
    const int*   eidx   = (const int*)  d_in[1];
    const float* eattr  = (const float*)d_in[2];
    const float* coords = (const float*)d_in[3];
    const int*   acls   = (const int*)  d_in[4];
    const float* BkTab  = (const float*)d_in[5];
    const float* posW   = (const float*)d_in[6];
    const float* posb   = (const float*)d_in[7];
    const float* W1s    = (const float*)d_in[8];
    const float* W1n    = (const float*)d_in[9];
    const float* b1     = (const float*)d_in[10];
    const float* gn1w   = (const float*)d_in[11];
    const float* gn1b   = (const float*)d_in[12];
    const float* gn1ms  = (const float*)d_in[13];
    const float* poolp  = (const float*)d_in[14];
    const float* W2s    = (const float*)d_in[15];
    const float* W2n    = (const float*)d_in[16];
    const float* b2     = (const float*)d_in[17];
    const float* gn2w   = (const float*)d_in[18];
    const float* gn2b   = (const float*)d_in[19];
    const float* gn2ms  = (const float*)d_in[20];
    const float* l1W    = (const float*)d_in[21];
    const float* l1b    = (const float*)d_in[22];
    const float* l2W    = (const float*)d_in[23];
    const float* l2b    = (const float*)d_in[24];

    const int* row  = eidx;
    const int* colp = eidx + ET_;

    float* W = (float*)d_ws;
    const size_t NTH = (size_t)NT_ * 64;        // 2,097,152 floats
    float* b0    = W;                           // y -> h2 -> agg2
    float* b1buf = W + 1*NTH;                   // hself -> hp(in-place) -> hp2 -> h3
    float* b2buf = W + 2*NTH;                   // Ae -> agg -> Ae2 -> y2
    float* b3buf = W + 3*NTH;                   // delta -> delta2 -> hs2
    float* p = W + 4*NTH;
    int2*  rowcsr = (int2*)p;        p += 2*(size_t)ET_;   // 8 MB
    int*   colcsr = (int*)p;         p += ET_;             // 4 MB
    int*   rowptr = (int*)p;         p += NT_ + 8;
    int*   colptr = (int*)p;         p += NT_ + 8;
    float* deg    = p;               p += NT_;
    float* deg2   = p;               p += NP2_;
    float* tanhv  = p;               p += NP2_;
    int*   perm   = (int*)p;         p += NP2_;
    int*   nmap   = (int*)p;         p += NT_;
    int*   cls2   = (int*)p;         p += NP2_;
    float* BkT    = p;               p += 6 * 4096;
    float* partial= p;               p += (size_t)G_ * 8 * 128;  // stats/readout partials
    float* meanv  = p;               p += G_ * 64;
    float* istdv  = p;               p += G_ * 64;

    // ---- prep ----
    k_bkT      <<<96,   256, 0, stream>>>(BkTab, BkT);
    k_build    <<<G_,   256, 0, stream>>>(row, colp, eattr, rowptr, colptr,
                                          rowcsr, colcsr, deg);
    hipMemsetAsync(nmap, 0xFF, NT_ * sizeof(int), stream);

    // ---- stage 1 ----
    k_gemm_dual<<<NT_/16,  256, 0, stream>>>(x, FIN_, W1n, W1s, b1,
                                             b0 /*y*/, b1buf /*hself*/);
    k_gaeA     <<<NT_/4,   256, 0, stream>>>(rowptr, rowcsr, coords, posW, posb,
                                             b2buf /*Ae*/);
    k_bkmv2    <<<NT_/4,   256, 0, stream>>>(b2buf /*Ae*/, acls, BkT, b3buf /*delta*/);
    k_gagg     <<<NT_/4,   256, 0, stream>>>(colptr, colcsr, b0 /*y*/, b2buf /*agg*/);
    k_gnstat   <<<G_*8,    256, 0, stream>>>(b1buf /*hself*/, b2buf /*agg*/, deg,
                                             partial, N_, 8, 64);
    k_gnfin    <<<G_,      64,  0, stream>>>(partial, gn1ms, 8, N_, meanv, istdv);
    k_gnprop   <<<NT_/4,   256, 0, stream>>>(b1buf /*hself*/, b2buf /*agg*/, deg,
                                             meanv, istdv, gn1w, gn1b,
                                             b3buf /*delta*/, acls, BkT,
                                             b1buf /*hp in-place*/);
    k_topk     <<<G_,      512, 0, stream>>>(b1buf /*hp*/, poolp, acls,
                                             perm, tanhv, nmap, cls2);
    k_gather   <<<NP2_*64/256, 256, 0, stream>>>(b1buf /*hp*/, perm, tanhv, b0 /*h2*/);

    // ---- stage 2 ----
    k_gae2     <<<NP2_/4,  256, 0, stream>>>(rowptr, rowcsr, perm, nmap,
                                             coords, posW, posb, b2buf /*Ae2*/);
    k_bkmv2    <<<NP2_/4,  256, 0, stream>>>(b2buf /*Ae2*/, cls2, BkT, b3buf /*delta2*/);
    k_prop2    <<<NP2_/4,  256, 0, stream>>>(b0 /*h2*/, b3buf /*delta2*/, b3buf /*delta2*/,
                                             cls2, BkT, b1buf /*hp2*/);
    k_gemm_dual<<<NP2_/16, 256, 0, stream>>>(b1buf /*hp2*/, 64, W2n, W2s, b2,
                                             b2buf /*y2*/, b3buf /*hs2*/);
    k_gagg2    <<<NP2_/4,  256, 0, stream>>>(colptr, colcsr, perm, nmap,
                                             b2buf /*y2*/, b0 /*agg2*/, deg2);
    k_gnstat   <<<G_*6,    256, 0, stream>>>(b3buf /*hs2*/, b0 /*agg2*/, deg2,
                                             partial, KP_, 6, 60);
    k_gnfin    <<<G_,      64,  0, stream>>>(partial, gn2ms, 6, KP_, meanv, istdv);
    k_gnapply  <<<NP2_*64/256, 256, 0, stream>>>(b3buf /*hs2*/, b0 /*agg2*/, deg2,
                                                 meanv, istdv, gn2w, gn2b,
                                                 b1buf /*h3*/);
    k_rpart    <<<G_*6,    256, 0, stream>>>(b1buf /*h3*/, partial, 6, 60);
    k_rfin     <<<G_,      64,  0, stream>>>(partial, 6, l1W, l1b, l2W, l2b,
                                             (float*)d_out);
}

// Round 5
// 604.494 us; speedup vs baseline: 3.7192x; 1.0902x over previous
//
#include <hip/hip_runtime.h>
#include <math.h>

#define G_    64
#define N_    512
#define H_    64
#define NT_   32768
#define ET_   1048576
#define EPG_  16384      // edges per graph
#define KP_   359
#define NP2_  22976
#define FIN_  128
#define ESL_  2048       // edges per build-phase block
#define BPB_  (EPG_/ESL_) // 8 build blocks per graph

// ---------------- transpose Bk_table: BkT[c][d*64+h] = Bk[c][h*64+d] ----------------
__global__ void k_bkT(const float* __restrict__ Bk, float* __restrict__ BkT) {
    int idx = blockIdx.x * 256 + threadIdx.x;          // 6*4096
    int c = idx >> 12, r = idx & 4095;
    int h = r >> 6, d = r & 63;
    BkT[c * 4096 + d * 64 + h] = Bk[c * 4096 + h * 64 + d];
}

// ---------------- build phase A: per-slice LDS histogram -> global hist ----------------
__global__ __launch_bounds__(256)
void k_hist(const int* __restrict__ row, const int* __restrict__ col,
            int* __restrict__ histR, int* __restrict__ histC) {
    __shared__ int hr[N_], hc[N_];
    int b = blockIdx.x, g = b >> 3, s = b & (BPB_ - 1);
    int t = threadIdx.x;
    for (int i = t; i < N_; i += 256) { hr[i] = 0; hc[i] = 0; }
    __syncthreads();
    int ebase = g * EPG_ + s * ESL_;
    for (int i = t; i < ESL_; i += 256) {
        atomicAdd(&hr[row[ebase + i] & (N_ - 1)], 1);
        atomicAdd(&hc[col[ebase + i] & (N_ - 1)], 1);
    }
    __syncthreads();
    int nbase = g * N_;
    for (int i = t; i < N_; i += 256) {
        if (hr[i]) atomicAdd(&histR[nbase + i], hr[i]);
        if (hc[i]) atomicAdd(&histC[nbase + i], hc[i]);
    }
}

// ---------------- build phase B: per-graph exclusive scan -> ptrs + cursors + deg ----------------
__global__ __launch_bounds__(256)
void k_scan(const int* __restrict__ histR, const int* __restrict__ histC,
            int* __restrict__ rowptr, int* __restrict__ colptr,
            int* __restrict__ cursR, int* __restrict__ cursC,
            float* __restrict__ deg) {
    __shared__ int hr[N_], hc[N_];
    int g = blockIdx.x, t = threadIdx.x;
    int nbase = g * N_;
    for (int i = t; i < N_; i += 256) {
        hr[i] = histR[nbase + i];
        int c = histC[nbase + i];
        hc[i] = c;
        deg[nbase + i] = (float)c;
    }
    __syncthreads();
    int wave = t >> 6, lane = t & 63;
    if (wave < 2) {
        int* h = wave ? hc : hr;
        int base8 = lane * 8;
        int loc[8];
        int tot = 0;
        #pragma unroll
        for (int i = 0; i < 8; i++) { int v = h[base8 + i]; loc[i] = tot; tot += v; }
        int pref = tot;
        for (int off = 1; off < 64; off <<= 1) {
            int u = __shfl_up(pref, off);
            if (lane >= off) pref += u;
        }
        pref -= tot;   // exclusive
        #pragma unroll
        for (int i = 0; i < 8; i++) h[base8 + i] = pref + loc[i];
    }
    __syncthreads();
    int ebase = g * EPG_;
    for (int i = t; i < N_; i += 256) {
        int rp = ebase + hr[i], cp = ebase + hc[i];
        rowptr[nbase + i] = rp;  cursR[nbase + i] = rp;
        colptr[nbase + i] = cp;  cursC[nbase + i] = cp;
    }
    if (g == 0 && t == 0) { rowptr[NT_] = ET_; colptr[NT_] = ET_; }
}

// ---------------- build phase C: scatter via global cursors ----------------
__global__ __launch_bounds__(256)
void k_scatter(const int* __restrict__ row, const int* __restrict__ col,
               const float* __restrict__ ea,
               int* __restrict__ cursR, int* __restrict__ cursC,
               int2* __restrict__ rowcsr, int* __restrict__ colcsr) {
    int b = blockIdx.x, g = b >> 3, s = b & (BPB_ - 1);
    int t = threadIdx.x;
    int ebase = g * EPG_ + s * ESL_;
    for (int i = t; i < ESL_; i += 256) {
        int rg = row[ebase + i], cg = col[ebase + i];
        float w = ea[ebase + i];
        int pr = atomicAdd(&cursR[rg], 1);
        rowcsr[pr] = make_int2(cg, __float_as_int(w));
        int pc = atomicAdd(&cursC[cg], 1);
        colcsr[pc] = rg;
    }
}

// ---------------- dual GEMM: outA = in@Wa, outB = in@Wb + bias (32 rows/block) ----------------
__global__ __launch_bounds__(256)
void k_gemm_dual(const float* __restrict__ in, int K,
                 const float* __restrict__ Wa, const float* __restrict__ Wb,
                 const float* __restrict__ bias,
                 float* __restrict__ outA, float* __restrict__ outB) {
    __shared__ float inT[32 * FIN_];
    int row0 = blockIdx.x * 32;
    int t = threadIdx.x;
    for (int idx = t; idx < 32 * K; idx += 256) inT[idx] = in[row0 * K + idx];
    __syncthreads();
    int c = t & 63, rb = t >> 6;            // wave rb handles rows rb*8 .. rb*8+7
    const float* ip = inT + (rb * 8) * K;
    float aA[8] = {0,0,0,0,0,0,0,0};
    float aB[8] = {0,0,0,0,0,0,0,0};
    for (int k = 0; k < K; k += 4) {
        float wa0 = Wa[(k+0)*64 + c], wa1 = Wa[(k+1)*64 + c];
        float wa2 = Wa[(k+2)*64 + c], wa3 = Wa[(k+3)*64 + c];
        float wb0 = Wb[(k+0)*64 + c], wb1 = Wb[(k+1)*64 + c];
        float wb2 = Wb[(k+2)*64 + c], wb3 = Wb[(k+3)*64 + c];
        #pragma unroll
        for (int r = 0; r < 8; r++) {
            float4 xv = *(const float4*)&ip[r*K + k];
            aA[r] += xv.x*wa0; aB[r] += xv.x*wb0;
            aA[r] += xv.y*wa1; aB[r] += xv.y*wb1;
            aA[r] += xv.z*wa2; aB[r] += xv.z*wb2;
            aA[r] += xv.w*wa3; aB[r] += xv.w*wb3;
        }
    }
    float bv = bias[c];
    #pragma unroll
    for (int r = 0; r < 8; r++) {
        int node = row0 + rb*8 + r;
        outA[node*64 + c] = aA[r];
        outB[node*64 + c] = aB[r] + bv;
    }
}

// ---------------- stage-1 Ae gather (e recomputed on the fly) ----------------
__global__ __launch_bounds__(256)
void k_gaeA(const int* __restrict__ rowptr, const int2* __restrict__ rcsr,
            const float* __restrict__ coords,
            const float* __restrict__ posW, const float* __restrict__ posb,
            float* __restrict__ Ae) {
    int node = blockIdx.x * 4 + (threadIdx.x >> 6);
    int lane = threadIdx.x & 63;
    float w0 = posW[0*64 + lane], w1 = posW[1*64 + lane], w2 = posW[2*64 + lane];
    float pb = posb[lane];
    int start = rowptr[node], end = rowptr[node + 1];
    float acc = 0.f;
    #pragma unroll 4
    for (int k = start; k < end; k++) {
        int2 ent = rcsr[k];
        int c = ent.x;
        float w = __int_as_float(ent.y);
        float e = pb + coords[c*3+0]*w0 + coords[c*3+1]*w1 + coords[c*3+2]*w2;
        acc += w * e;
    }
    Ae[node*64 + lane] = acc;
}

// ---------------- stage-1 agg gather ----------------
__global__ __launch_bounds__(256)
void k_gagg(const int* __restrict__ colptr, const int* __restrict__ ccsr,
            const float* __restrict__ y, float* __restrict__ agg) {
    int node = blockIdx.x * 4 + (threadIdx.x >> 6);
    int lane = threadIdx.x & 63;
    int start = colptr[node], end = colptr[node + 1];
    float acc = 0.f;
    #pragma unroll 4
    for (int k = start; k < end; k++) {
        int r = ccsr[k];
        acc += y[r*64 + lane];
    }
    agg[node*64 + lane] = acc;
}

// ---------------- per-node matvec via BkT ----------------
__global__ __launch_bounds__(256)
void k_bkmv2(const float* __restrict__ in, const int* __restrict__ cls,
             const float* __restrict__ BkT, float* __restrict__ out) {
    int node = blockIdx.x * 4 + (threadIdx.x >> 6);
    int lane = threadIdx.x & 63;
    const float* B  = BkT + cls[node] * 4096;   // [d*64 + h]
    const float* iv = in + node * 64;
    float acc = 0.f;
    #pragma unroll 8
    for (int d = 0; d < 64; d++) acc += B[d*64 + lane] * iv[d];
    out[node*64 + lane] = acc;
}

// ---------------- stage-2 propagate ----------------
__global__ __launch_bounds__(256)
void k_prop2(const float* __restrict__ inA, const float* __restrict__ inB,
             const float* __restrict__ delta, const int* __restrict__ cls,
             const float* __restrict__ BkT, float* __restrict__ out) {
    int node = blockIdx.x * 4 + (threadIdx.x >> 6);
    int lane = threadIdx.x & 63;
    const float* B  = BkT + cls[node] * 4096;
    const float* a  = inA + node * 64;
    const float* b  = inB ? inB + node * 64 : nullptr;
    float acc = 0.f, s = 0.f;
    #pragma unroll 8
    for (int j = 0; j < 64; j++) {
        float hj = a[j] + (b ? b[j] : 0.f);
        s   += hj;
        acc += B[j*64 + lane] * hj;
    }
    out[node*64 + lane] = acc + delta[node*64 + lane] * s;
}

// ---------------- graph_norm stats: one-pass sum & sumsq partials ----------------
__global__ __launch_bounds__(256)
void k_gnstat(const float* __restrict__ hs, const float* __restrict__ agg,
              const float* __restrict__ deg, float* __restrict__ partial,
              int NPG, int CH, int npc) {
    __shared__ float r1[256], r2[256];
    int b = blockIdx.x;
    int g = b / CH, chunk = b % CH;
    int t = threadIdx.x, c = t & 63, grp = t >> 6;
    int n0 = chunk * npc;
    int nend = min(n0 + npc, NPG);
    float s1 = 0.f, s2 = 0.f;
    for (int n = n0 + grp; n < nend; n += 4) {
        int node = g * NPG + n;
        float v = hs[node*64 + c] + agg[node*64 + c] / fmaxf(deg[node], 1.f);
        s1 += v; s2 += v * v;
    }
    r1[t] = s1; r2[t] = s2;
    __syncthreads();
    if (grp == 0) {
        partial[b*128 + c]      = r1[c] + r1[64+c] + r1[128+c] + r1[192+c];
        partial[b*128 + 64 + c] = r2[c] + r2[64+c] + r2[128+c] + r2[192+c];
    }
}

// ---------------- graph_norm finalize: mval = ms*mean, istd ----------------
__global__ void k_gnfin(const float* __restrict__ partial, const float* __restrict__ ms,
                        int CH, int NPG,
                        float* __restrict__ mval, float* __restrict__ istdv) {
    int g = blockIdx.x, t = threadIdx.x;   // 64 threads
    float s1 = 0.f, s2 = 0.f;
    for (int i = 0; i < CH; i++) {
        s1 += partial[(g*CH + i)*128 + t];
        s2 += partial[(g*CH + i)*128 + 64 + t];
    }
    float m = s1 / (float)NPG, q = s2 / (float)NPG, msv = ms[t];
    float var = q - msv * m * m * (2.f - msv);   // E[(h-ms*m)^2]
    mval[g*64 + t]  = msv * m;
    istdv[g*64 + t] = rsqrtf(var + 1e-5f);
}

// ---------------- stage-1 fused: gn-apply + elu + (+delta) + propagate ----------------
__global__ __launch_bounds__(256)
void k_gnprop(const float* __restrict__ hself, const float* __restrict__ agg,
              const float* __restrict__ deg,
              const float* __restrict__ mval, const float* __restrict__ istdv,
              const float* __restrict__ w, const float* __restrict__ b,
              const float* __restrict__ delta, const int* __restrict__ cls,
              const float* __restrict__ BkT, float* __restrict__ out) {
    __shared__ float hT[256];
    int t = threadIdx.x;
    int node = blockIdx.x * 4 + (t >> 6);
    int lane = t & 63;
    int g = node >> 9;                       // N_=512 nodes/graph
    float v = hself[node*64 + lane] + agg[node*64 + lane] / fmaxf(deg[node], 1.f);
    v = w[lane] * (v - mval[g*64 + lane]) * istdv[g*64 + lane] + b[lane];
    v = v > 0.f ? v : expm1f(v);
    float d = delta[node*64 + lane];
    v += d;
    hT[t] = v;
    __syncthreads();
    float s = v;
    #pragma unroll
    for (int off = 32; off; off >>= 1) s += __shfl_down(s, off);
    s = __shfl(s, 0);
    const float* B  = BkT + cls[node] * 4096;
    const float* hv = hT + (t & ~63);
    float acc = 0.f;
    #pragma unroll 8
    for (int j = 0; j < 64; j++) acc += B[j*64 + lane] * hv[j];
    out[node*64 + lane] = acc + d * s;
}

// ---------------- stage-2 gn apply + elu ----------------
__global__ void k_gnapply(const float* __restrict__ hs, const float* __restrict__ agg,
                          const float* __restrict__ deg,
                          const float* __restrict__ mval, const float* __restrict__ istdv,
                          const float* __restrict__ w, const float* __restrict__ b,
                          float* __restrict__ out) {
    int gid = blockIdx.x * 256 + threadIdx.x;    // NP2*64
    int j = gid >> 6, lane = gid & 63;
    int g = j / KP_;
    float v = hs[gid] + agg[gid] / fmaxf(deg[j], 1.f);
    v = w[lane] * (v - mval[g*64 + lane]) * istdv[g*64 + lane] + b[lane];
    out[gid] = v > 0.f ? v : expm1f(v);
}

// ---------------- top-k per graph (desc score, ties by lower idx) ----------------
__global__ void k_topk(const float* __restrict__ hp, const float* __restrict__ p,
                       const int* __restrict__ cls,
                       int* __restrict__ perm, float* __restrict__ tanhv,
                       int* __restrict__ node_map, int* __restrict__ class2) {
    __shared__ float key[N_];
    __shared__ int   idxS[N_];
    __shared__ float pS[64];
    __shared__ float nrm;
    int g = blockIdx.x, t = threadIdx.x;
    if (t < 64) pS[t] = p[t];
    __syncthreads();
    if (t == 0) {
        float s = 0.f;
        for (int i = 0; i < 64; i++) s += pS[i] * pS[i];
        nrm = sqrtf(s);
    }
    __syncthreads();
    {
        float acc = 0.f;
        const float* hv = hp + (size_t)(g*N_ + t) * 64;
        for (int cdx = 0; cdx < 64; cdx++) acc += hv[cdx] * pS[cdx];
        key[t]  = acc / nrm;
        idxS[t] = t;
    }
    __syncthreads();
    for (int k = 2; k <= N_; k <<= 1) {
        for (int j = k >> 1; j > 0; j >>= 1) {
            int i = t, ixj = i ^ j;
            if (ixj > i) {
                float ki = key[i], kj = key[ixj];
                int   ii = idxS[i], ij = idxS[ixj];
                bool before = (ki > kj) || (ki == kj && ii < ij);
                bool dir = ((i & k) == 0);
                if (dir ? !before : before) {
                    key[i] = kj; key[ixj] = ki;
                    idxS[i] = ij; idxS[ixj] = ii;
                }
            }
            __syncthreads();
        }
    }
    if (t < KP_) {
        int orig  = idxS[t];
        int gnode = g * N_ + orig;
        int pj    = g * KP_ + t;
        perm[pj]     = gnode;
        tanhv[pj]    = tanhf(key[t]);
        node_map[gnode] = pj;
        class2[pj]   = cls[gnode];
    }
}

// ---------------- pooled gather: h2[j] = hp[perm[j]] * tanhv[j] ----------------
__global__ void k_gather(const float* __restrict__ hp, const int* __restrict__ perm,
                         const float* __restrict__ tanhv, float* __restrict__ h2) {
    int gid = blockIdx.x * 256 + threadIdx.x;   // NP2*64
    int j = gid >> 6, c = gid & 63;
    h2[gid] = hp[perm[j]*64 + c] * tanhv[j];
}

// ---------------- stage-2 Ae2 gather ----------------
__global__ __launch_bounds__(256)
void k_gae2(const int* __restrict__ rowptr, const int2* __restrict__ rcsr,
            const int* __restrict__ perm, const int* __restrict__ nmap,
            const float* __restrict__ coords,
            const float* __restrict__ posW, const float* __restrict__ posb,
            float* __restrict__ Ae2) {
    int j = blockIdx.x * 4 + (threadIdx.x >> 6);
    int lane = threadIdx.x & 63;
    float w0 = posW[0*64 + lane], w1 = posW[1*64 + lane], w2 = posW[2*64 + lane];
    float pb = posb[lane];
    int orig = perm[j];
    int start = rowptr[orig], end = rowptr[orig + 1];
    float acc = 0.f;
    #pragma unroll 4
    for (int k = start; k < end; k++) {
        int2 ent = rcsr[k];
        int c = ent.x;
        if (nmap[c] >= 0) {
            acc += pb + coords[c*3+0]*w0 + coords[c*3+1]*w1 + coords[c*3+2]*w2;
        }
    }
    Ae2[j*64 + lane] = acc;
}

// ---------------- stage-2 agg gather + deg2 ----------------
__global__ __launch_bounds__(256)
void k_gagg2(const int* __restrict__ colptr, const int* __restrict__ ccsr,
             const int* __restrict__ perm, const int* __restrict__ nmap,
             const float* __restrict__ y2,
             float* __restrict__ agg2, float* __restrict__ deg2) {
    int j = blockIdx.x * 4 + (threadIdx.x >> 6);
    int lane = threadIdx.x & 63;
    int orig = perm[j];
    int start = colptr[orig], end = colptr[orig + 1];
    float acc = 0.f;
    int cnt = 0;
    #pragma unroll 4
    for (int k = start; k < end; k++) {
        int s2 = nmap[ccsr[k]];
        if (s2 >= 0) {
            acc += y2[s2*64 + lane];
            cnt++;
        }
    }
    agg2[j*64 + lane] = acc;
    if (lane == 0) deg2[j] = (float)cnt;
}

// ---------------- readout partials: sum & max per (graph, chunk, channel) ----------------
__global__ __launch_bounds__(256)
void k_rpart(const float* __restrict__ h3, float* __restrict__ part,
             int CH, int npc) {
    __shared__ float r1[256], r2[256];
    int b = blockIdx.x;
    int g = b / CH, chunk = b % CH;
    int t = threadIdx.x, c = t & 63, grp = t >> 6;
    int n0 = chunk * npc, nend = min(n0 + npc, KP_);
    float s = 0.f, m = -1e30f;
    for (int n = n0 + grp; n < nend; n += 4) {
        float v = h3[(g*KP_ + n)*64 + c];
        s += v; m = fmaxf(m, v);
    }
    r1[t] = s; r2[t] = m;
    __syncthreads();
    if (grp == 0) {
        part[b*128 + c]      = r1[c] + r1[64+c] + r1[128+c] + r1[192+c];
        part[b*128 + 64 + c] = fmaxf(fmaxf(r2[c], r2[64+c]), fmaxf(r2[128+c], r2[192+c]));
    }
}

// ---------------- readout finalize: lin1 relu -> lin2 -> log_softmax ----------------
__global__ void k_rfin(const float* __restrict__ part, int CH,
                       const float* __restrict__ l1W, const float* __restrict__ l1b,
                       const float* __restrict__ l2W, const float* __restrict__ l2b,
                       float* __restrict__ out) {
    __shared__ float gv[192], rS[64];
    int g = blockIdx.x, t = threadIdx.x;   // 64 threads
    float s = 0.f, m = -1e30f;
    for (int i = 0; i < CH; i++) {
        s += part[(g*CH + i)*128 + t];
        m = fmaxf(m, part[(g*CH + i)*128 + 64 + t]);
    }
    gv[t] = s / (float)KP_;
    gv[64 + t] = m;
    gv[128 + t] = s;
    __syncthreads();
    float acc = l1b[t];
    for (int k = 0; k < 192; k++) acc += gv[k] * l1W[k*64 + t];
    rS[t] = fmaxf(acc, 0.f);
    __syncthreads();
    if (t == 0) {
        float l0 = l2b[0], l1v = l2b[1];
        for (int hh = 0; hh < 64; hh++) { l0 += rS[hh]*l2W[hh*2+0]; l1v += rS[hh]*l2W[hh*2+1]; }
        float mx  = fmaxf(l0, l1v);
        float lse = mx + logf(expf(l0 - mx) + expf(l1v - mx));
        out[g*2 + 0] = l0  - lse;
        out[g*2 + 1] = l1v - lse;
    }
}

extern "C" void kernel_launch(void* const* d_in, const int* in_sizes, int n_in,
                              void* d_out, int out_size, void* d_ws, size_t ws_size,
                              hipStream_t stream) {
    const float* x      = (const float*)d_in[0];
    const int*   eidx   = (const int*)  d_in[1];
    const float* eattr  = (const float*)d_in[2];
    const float* coords = (const float*)d_in[3];
    const int*   acls   = (const int*)  d_in[4];
    const float* BkTab  = (const float*)d_in[5];
    const float* posW   = (const float*)d_in[6];
    const float* posb   = (const float*)d_in[7];
    const float* W1s    = (const float*)d_in[8];
    const float* W1n    = (const float*)d_in[9];
    const float* b1     = (const float*)d_in[10];
    const float* gn1w   = (const float*)d_in[11];
    const float* gn1b   = (const float*)d_in[12];
    const float* gn1ms  = (const float*)d_in[13];
    const float* poolp  = (const float*)d_in[14];
    const float* W2s    = (const float*)d_in[15];
    const float* W2n    = (const float*)d_in[16];
    const float* b2     = (const float*)d_in[17];
    const float* gn2w   = (const float*)d_in[18];
    const float* gn2b   = (const float*)d_in[19];
    const float* gn2ms  = (const float*)d_in[20];
    const float* l1W    = (const float*)d_in[21];
    const float* l1b    = (const float*)d_in[22];
    const float* l2W    = (const float*)d_in[23];
    const float* l2b    = (const float*)d_in[24];

    const int* row  = eidx;
    const int* colp = eidx + ET_;

    float* W = (float*)d_ws;
    const size_t NTH = (size_t)NT_ * 64;        // 2,097,152 floats
    float* b0    = W;                           // y -> h2 -> agg2
    float* b1buf = W + 1*NTH;                   // hself -> hp(in-place) -> hp2 -> h3
    float* b2buf = W + 2*NTH;                   // Ae -> agg -> Ae2 -> y2
    float* b3buf = W + 3*NTH;                   // delta -> delta2 -> hs2
    float* p = W + 4*NTH;
    int2*  rowcsr = (int2*)p;        p += 2*(size_t)ET_;   // 8 MB
    int*   colcsr = (int*)p;         p += ET_;             // 4 MB
    int*   rowptr = (int*)p;         p += NT_ + 8;
    int*   colptr = (int*)p;         p += NT_ + 8;
    int*   histR  = (int*)p;         p += NT_;
    int*   histC  = (int*)p;         p += NT_;
    int*   cursR  = (int*)p;         p += NT_;
    int*   cursC  = (int*)p;         p += NT_;
    float* deg    = p;               p += NT_;
    float* deg2   = p;               p += NP2_;
    float* tanhv  = p;               p += NP2_;
    int*   perm   = (int*)p;         p += NP2_;
    int*   nmap   = (int*)p;         p += NT_;
    int*   cls2   = (int*)p;         p += NP2_;
    float* BkT    = p;               p += 6 * 4096;
    float* partial= p;               p += (size_t)G_ * 8 * 128;  // stats/readout partials
    float* meanv  = p;               p += G_ * 64;
    float* istdv  = p;               p += G_ * 64;

    // ---- prep ----
    hipMemsetAsync(histR, 0, 2 * NT_ * sizeof(int), stream);   // histR + histC
    hipMemsetAsync(nmap, 0xFF, NT_ * sizeof(int), stream);
    k_bkT      <<<96,       256, 0, stream>>>(BkTab, BkT);
    k_hist     <<<G_*BPB_,  256, 0, stream>>>(row, colp, histR, histC);
    k_scan     <<<G_,       256, 0, stream>>>(histR, histC, rowptr, colptr,
                                              cursR, cursC, deg);
    k_scatter  <<<G_*BPB_,  256, 0, stream>>>(row, colp, eattr, cursR, cursC,
                                              rowcsr, colcsr);

    // ---- stage 1 ----
    k_gemm_dual<<<NT_/32,  256, 0, stream>>>(x, FIN_, W1n, W1s, b1,
                                             b0 /*y*/, b1buf /*hself*/);
    k_gaeA     <<<NT_/4,   256, 0, stream>>>(rowptr, rowcsr, coords, posW, posb,
                                             b2buf /*Ae*/);
    k_bkmv2    <<<NT_/4,   256, 0, stream>>>(b2buf /*Ae*/, acls, BkT, b3buf /*delta*/);
    k_gagg     <<<NT_/4,   256, 0, stream>>>(colptr, colcsr, b0 /*y*/, b2buf /*agg*/);
    k_gnstat   <<<G_*8,    256, 0, stream>>>(b1buf /*hself*/, b2buf /*agg*/, deg,
                                             partial, N_, 8, 64);
    k_gnfin    <<<G_,      64,  0, stream>>>(partial, gn1ms, 8, N_, meanv, istdv);
    k_gnprop   <<<NT_/4,   256, 0, stream>>>(b1buf /*hself*/, b2buf /*agg*/, deg,
                                             meanv, istdv, gn1w, gn1b,
                                             b3buf /*delta*/, acls, BkT,
                                             b1buf /*hp in-place*/);
    k_topk     <<<G_,      512, 0, stream>>>(b1buf /*hp*/, poolp, acls,
                                             perm, tanhv, nmap, cls2);
    k_gather   <<<NP2_*64/256, 256, 0, stream>>>(b1buf /*hp*/, perm, tanhv, b0 /*h2*/);

    // ---- stage 2 ----
    k_gae2     <<<NP2_/4,  256, 0, stream>>>(rowptr, rowcsr, perm, nmap,
                                             coords, posW, posb, b2buf /*Ae2*/);
    k_bkmv2    <<<NP2_/4,  256, 0, stream>>>(b2buf /*Ae2*/, cls2, BkT, b3buf /*delta2*/);
    k_prop2    <<<NP2_/4,  256, 0, stream>>>(b0 /*h2*/, b3buf /*delta2*/, b3buf /*delta2*/,
                                             cls2, BkT, b1buf /*hp2*/);
    k_gemm_dual<<<NP2_/32, 256, 0, stream>>>(b1buf /*hp2*/, 64, W2n, W2s, b2,
                                             b2buf /*y2*/, b3buf /*hs2*/);
    k_gagg2    <<<NP2_/4,  256, 0, stream>>>(colptr, colcsr, perm, nmap,
                                             b2buf /*y2*/, b0 /*agg2*/, deg2);
    k_gnstat   <<<G_*6,    256, 0, stream>>>(b3buf /*hs2*/, b0 /*agg2*/, deg2,
                                             partial, KP_, 6, 60);
    k_gnfin    <<<G_,      64,  0, stream>>>(partial, gn2ms, 6, KP_, meanv, istdv);
    k_gnapply  <<<NP2_*64/256, 256, 0, stream>>>(b3buf /*hs2*/, b0 /*agg2*/, deg2,
                                                 meanv, istdv, gn2w, gn2b,
                                                 b1buf /*h3*/);
    k_rpart    <<<G_*6,    256, 0, stream>>>(b1buf /*h3*/, partial, 6, 60);
    k_rfin     <<<G_,      64,  0, stream>>>(partial, 6, l1W, l1b, l2W, l2b,
                                             (float*)d_out);
}

// Round 6
// 404.362 us; speedup vs baseline: 5.5599x; 1.4949x over previous
//
#include <hip/hip_runtime.h>
#include <math.h>

#define G_    64
#define N_    512
#define H_    64
#define NT_   32768
#define ET_   1048576
#define EPG_  16384      // edges per graph
#define KP_   359
#define NP2_  22976
#define FIN_  128
#define ESL_  2048       // edges per build-phase block
#define BPB_  (EPG_/ESL_) // 8 build blocks per graph

// ---------------- transpose Bk_table: BkT[c][d*64+h] = Bk[c][h*64+d] ----------------
__global__ void k_bkT(const float* __restrict__ Bk, float* __restrict__ BkT) {
    int idx = blockIdx.x * 256 + threadIdx.x;          // 6*4096
    int c = idx >> 12, r = idx & 4095;
    int h = r >> 6, d = r & 63;
    BkT[c * 4096 + d * 64 + h] = Bk[c * 4096 + h * 64 + d];
}

// ---------------- precompute delta tables: PT[c][i][h] = sum_d Bk_c[h,d]*basis_i[d]
// basis 0..2 = posW rows, basis 3 = posb
__global__ void k_pre(const float* __restrict__ Bk, const float* __restrict__ posW,
                      const float* __restrict__ posb, float* __restrict__ PT) {
    int c = blockIdx.x;                  // 6
    int t = threadIdx.x;                 // 256
    int i = t >> 6, h = t & 63;
    const float* B = Bk + c * 4096 + h * 64;
    float acc = 0.f;
    for (int d = 0; d < 64; d++) {
        float vd = (i < 3) ? posW[i*64 + d] : posb[d];
        acc += B[d] * vd;
    }
    PT[c*256 + i*64 + h] = acc;
}

// ---------------- build phase A: per-slice LDS histogram -> global hist ----------------
__global__ __launch_bounds__(256)
void k_hist(const int* __restrict__ row, const int* __restrict__ col,
            int* __restrict__ histR, int* __restrict__ histC) {
    __shared__ int hr[N_], hc[N_];
    int b = blockIdx.x, g = b >> 3, s = b & (BPB_ - 1);
    int t = threadIdx.x;
    for (int i = t; i < N_; i += 256) { hr[i] = 0; hc[i] = 0; }
    __syncthreads();
    int ebase = g * EPG_ + s * ESL_;
    for (int i = t; i < ESL_; i += 256) {
        atomicAdd(&hr[row[ebase + i] & (N_ - 1)], 1);
        atomicAdd(&hc[col[ebase + i] & (N_ - 1)], 1);
    }
    __syncthreads();
    int nbase = g * N_;
    for (int i = t; i < N_; i += 256) {
        if (hr[i]) atomicAdd(&histR[nbase + i], hr[i]);
        if (hc[i]) atomicAdd(&histC[nbase + i], hc[i]);
    }
}

// ---------------- build phase B: scan -> ptrs + cursors (in-place into hist) + deg ----------------
__global__ __launch_bounds__(256)
void k_scan(int* __restrict__ histR, int* __restrict__ histC,
            int* __restrict__ rowptr, int* __restrict__ colptr,
            float* __restrict__ deg) {
    __shared__ int hr[N_], hc[N_];
    int g = blockIdx.x, t = threadIdx.x;
    int nbase = g * N_;
    for (int i = t; i < N_; i += 256) {
        hr[i] = histR[nbase + i];
        int c = histC[nbase + i];
        hc[i] = c;
        deg[nbase + i] = (float)c;
    }
    __syncthreads();
    int wave = t >> 6, lane = t & 63;
    if (wave < 2) {
        int* h = wave ? hc : hr;
        int base8 = lane * 8;
        int loc[8];
        int tot = 0;
        #pragma unroll
        for (int i = 0; i < 8; i++) { int v = h[base8 + i]; loc[i] = tot; tot += v; }
        int pref = tot;
        for (int off = 1; off < 64; off <<= 1) {
            int u = __shfl_up(pref, off);
            if (lane >= off) pref += u;
        }
        pref -= tot;   // exclusive
        #pragma unroll
        for (int i = 0; i < 8; i++) h[base8 + i] = pref + loc[i];
    }
    __syncthreads();
    int ebase = g * EPG_;
    for (int i = t; i < N_; i += 256) {
        int rp = ebase + hr[i], cp = ebase + hc[i];
        rowptr[nbase + i] = rp;  histR[nbase + i] = rp;   // hist now = cursors
        colptr[nbase + i] = cp;  histC[nbase + i] = cp;
    }
    if (g == 0 && t == 0) { rowptr[NT_] = ET_; colptr[NT_] = ET_; }
}

// ---------------- build phase C: scatter via global cursors ----------------
__global__ __launch_bounds__(256)
void k_scatter(const int* __restrict__ row, const int* __restrict__ col,
               const float* __restrict__ ea,
               int* __restrict__ cursR, int* __restrict__ cursC,
               int2* __restrict__ rowcsr, int* __restrict__ colcsr) {
    int b = blockIdx.x, g = b >> 3, s = b & (BPB_ - 1);
    int t = threadIdx.x;
    int ebase = g * EPG_ + s * ESL_;
    for (int i = t; i < ESL_; i += 256) {
        int rg = row[ebase + i], cg = col[ebase + i];
        float w = ea[ebase + i];
        int pr = atomicAdd(&cursR[rg], 1);
        rowcsr[pr] = make_int2(cg, __float_as_int(w));
        int pc = atomicAdd(&cursC[cg], 1);
        colcsr[pc] = rg;
    }
}

// ---------------- dual GEMM: outA = in@Wa (rows optionally scattered), outB = in@Wb + bias
__global__ __launch_bounds__(256)
void k_gemm_dual(const float* __restrict__ in, int K,
                 const float* __restrict__ Wa, const float* __restrict__ Wb,
                 const float* __restrict__ bias, const int* __restrict__ permA,
                 float* __restrict__ outA, float* __restrict__ outB) {
    __shared__ float inT[32 * FIN_];
    int row0 = blockIdx.x * 32;
    int t = threadIdx.x;
    for (int idx = t; idx < 32 * K; idx += 256) inT[idx] = in[row0 * K + idx];
    __syncthreads();
    int c = t & 63, rb = t >> 6;            // wave rb handles rows rb*8 .. rb*8+7
    const float* ip = inT + (rb * 8) * K;
    float aA[8] = {0,0,0,0,0,0,0,0};
    float aB[8] = {0,0,0,0,0,0,0,0};
    for (int k = 0; k < K; k += 4) {
        float wa0 = Wa[(k+0)*64 + c], wa1 = Wa[(k+1)*64 + c];
        float wa2 = Wa[(k+2)*64 + c], wa3 = Wa[(k+3)*64 + c];
        float wb0 = Wb[(k+0)*64 + c], wb1 = Wb[(k+1)*64 + c];
        float wb2 = Wb[(k+2)*64 + c], wb3 = Wb[(k+3)*64 + c];
        #pragma unroll
        for (int r = 0; r < 8; r++) {
            float4 xv = *(const float4*)&ip[r*K + k];
            aA[r] += xv.x*wa0; aB[r] += xv.x*wb0;
            aA[r] += xv.y*wa1; aB[r] += xv.y*wb1;
            aA[r] += xv.z*wa2; aB[r] += xv.z*wb2;
            aA[r] += xv.w*wa3; aB[r] += xv.w*wb3;
        }
    }
    float bv = bias[c];
    #pragma unroll
    for (int r = 0; r < 8; r++) {
        int node = row0 + rb*8 + r;
        int rowA = permA ? permA[node] : node;
        outA[rowA*64 + c] = aA[r];
        outB[node*64 + c] = aB[r] + bv;
    }
}

// ---------------- stage-1 node sums: nsum[n] = (Σ w*cx, Σ w*cy, Σ w*cz, Σ w) over out-edges
__global__ __launch_bounds__(256)
void k_nsum1(const int* __restrict__ rowptr, const int2* __restrict__ rcsr,
             const float* __restrict__ coords, float4* __restrict__ nsum) {
    int node = blockIdx.x * 4 + (threadIdx.x >> 6);
    int lane = threadIdx.x & 63;
    int start = rowptr[node], end = rowptr[node + 1];
    float sx = 0.f, sy = 0.f, sz = 0.f, sw = 0.f;
    for (int k = start + lane; k < end; k += 64) {
        int2 ent = rcsr[k];
        int c = ent.x;
        float w = __int_as_float(ent.y);
        sx += w * coords[c*3+0];
        sy += w * coords[c*3+1];
        sz += w * coords[c*3+2];
        sw += w;
    }
    #pragma unroll
    for (int off = 32; off; off >>= 1) {
        sx += __shfl_xor(sx, off); sy += __shfl_xor(sy, off);
        sz += __shfl_xor(sz, off); sw += __shfl_xor(sw, off);
    }
    if (lane == 0) nsum[node] = make_float4(sx, sy, sz, sw);
}

// ---------------- stage-1 agg gather ----------------
__global__ __launch_bounds__(256)
void k_gagg(const int* __restrict__ colptr, const int* __restrict__ ccsr,
            const float* __restrict__ y, float* __restrict__ agg) {
    int node = blockIdx.x * 4 + (threadIdx.x >> 6);
    int lane = threadIdx.x & 63;
    int start = colptr[node], end = colptr[node + 1];
    float acc = 0.f;
    #pragma unroll 4
    for (int k = start; k < end; k++) {
        int r = ccsr[k];
        acc += y[r*64 + lane];
    }
    agg[node*64 + lane] = acc;
}

// ---------------- graph_norm stats: one-pass sum & sumsq partials ----------------
__global__ __launch_bounds__(256)
void k_gnstat(const float* __restrict__ hs, const float* __restrict__ agg,
              const float* __restrict__ deg, float* __restrict__ partial,
              int NPG, int CH, int npc) {
    __shared__ float r1[256], r2[256];
    int b = blockIdx.x;
    int g = b / CH, chunk = b % CH;
    int t = threadIdx.x, c = t & 63, grp = t >> 6;
    int n0 = chunk * npc;
    int nend = min(n0 + npc, NPG);
    float s1 = 0.f, s2 = 0.f;
    for (int n = n0 + grp; n < nend; n += 4) {
        int node = g * NPG + n;
        float v = hs[node*64 + c] + agg[node*64 + c] / fmaxf(deg[node], 1.f);
        s1 += v; s2 += v * v;
    }
    r1[t] = s1; r2[t] = s2;
    __syncthreads();
    if (grp == 0) {
        partial[b*128 + c]      = r1[c] + r1[64+c] + r1[128+c] + r1[192+c];
        partial[b*128 + 64 + c] = r2[c] + r2[64+c] + r2[128+c] + r2[192+c];
    }
}

// ---------------- graph_norm finalize ----------------
__global__ void k_gnfin(const float* __restrict__ partial, const float* __restrict__ ms,
                        int CH, int NPG,
                        float* __restrict__ mval, float* __restrict__ istdv) {
    int g = blockIdx.x, t = threadIdx.x;   // 64 threads
    float s1 = 0.f, s2 = 0.f;
    for (int i = 0; i < CH; i++) {
        s1 += partial[(g*CH + i)*128 + t];
        s2 += partial[(g*CH + i)*128 + 64 + t];
    }
    float m = s1 / (float)NPG, q = s2 / (float)NPG, msv = ms[t];
    float var = q - msv * m * m * (2.f - msv);   // E[(h-ms*m)^2]
    mval[g*64 + t]  = msv * m;
    istdv[g*64 + t] = rsqrtf(var + 1e-5f);
}

// ---------------- stage-1 fused: gn-apply + elu + delta(from nsum) + propagate ----------------
__global__ __launch_bounds__(256)
void k_gnprop(const float* __restrict__ hself, const float* __restrict__ agg,
              const float* __restrict__ deg,
              const float* __restrict__ mval, const float* __restrict__ istdv,
              const float* __restrict__ w, const float* __restrict__ b,
              const float4* __restrict__ nsum, const int* __restrict__ cls,
              const float* __restrict__ PT, const float* __restrict__ BkT,
              float* __restrict__ out) {
    __shared__ float hT[256];
    int t = threadIdx.x;
    int node = blockIdx.x * 4 + (t >> 6);
    int lane = t & 63;
    int g = node >> 9;
    float4 s4 = nsum[node];
    int c = cls[node];
    const float* P = PT + c * 256;
    float d = s4.x*P[lane] + s4.y*P[64+lane] + s4.z*P[128+lane] + s4.w*P[192+lane];
    float v = hself[node*64 + lane] + agg[node*64 + lane] / fmaxf(deg[node], 1.f);
    v = w[lane] * (v - mval[g*64 + lane]) * istdv[g*64 + lane] + b[lane];
    v = v > 0.f ? v : expm1f(v);
    v += d;
    hT[t] = v;
    __syncthreads();
    float ssum = v;
    #pragma unroll
    for (int off = 32; off; off >>= 1) ssum += __shfl_xor(ssum, off);
    const float* B  = BkT + c * 4096;
    const float* hv = hT + (t & ~63);
    float acc = 0.f;
    #pragma unroll 8
    for (int j = 0; j < 64; j++) acc += B[j*64 + lane] * hv[j];
    out[node*64 + lane] = acc + d * ssum;
}

// ---------------- top-k per graph (desc score, ties by lower idx) ----------------
__global__ void k_topk(const float* __restrict__ hp, const float* __restrict__ p,
                       const int* __restrict__ cls,
                       int* __restrict__ perm, float* __restrict__ tanhv,
                       int* __restrict__ node_map, int* __restrict__ class2) {
    __shared__ float key[N_];
    __shared__ int   idxS[N_];
    __shared__ float pS[64];
    __shared__ float nrm;
    int g = blockIdx.x, t = threadIdx.x;
    if (t < 64) pS[t] = p[t];
    __syncthreads();
    if (t == 0) {
        float s = 0.f;
        for (int i = 0; i < 64; i++) s += pS[i] * pS[i];
        nrm = sqrtf(s);
    }
    __syncthreads();
    {
        float acc = 0.f;
        const float* hv = hp + (size_t)(g*N_ + t) * 64;
        for (int cdx = 0; cdx < 64; cdx++) acc += hv[cdx] * pS[cdx];
        key[t]  = acc / nrm;
        idxS[t] = t;
    }
    __syncthreads();
    for (int k = 2; k <= N_; k <<= 1) {
        for (int j = k >> 1; j > 0; j >>= 1) {
            int i = t, ixj = i ^ j;
            if (ixj > i) {
                float ki = key[i], kj = key[ixj];
                int   ii = idxS[i], ij = idxS[ixj];
                bool before = (ki > kj) || (ki == kj && ii < ij);
                bool dir = ((i & k) == 0);
                if (dir ? !before : before) {
                    key[i] = kj; key[ixj] = ki;
                    idxS[i] = ij; idxS[ixj] = ii;
                }
            }
            __syncthreads();
        }
    }
    if (t < KP_) {
        int orig  = idxS[t];
        int gnode = g * N_ + orig;
        int pj    = g * KP_ + t;
        perm[pj]     = gnode;
        tanhv[pj]    = tanhf(key[t]);
        node_map[gnode] = pj;
        class2[pj]   = cls[gnode];
    }
}

// ---------------- stage-2 per-node sums + deg2 (valid-masked) ----------------
__global__ __launch_bounds__(256)
void k_s2pre(const int* __restrict__ rowptr, const int2* __restrict__ rcsr,
             const int* __restrict__ colptr, const int* __restrict__ ccsr,
             const int* __restrict__ perm, const int* __restrict__ nmap,
             const float* __restrict__ coords,
             float4* __restrict__ nsum2, float* __restrict__ deg2) {
    int j = blockIdx.x * 4 + (threadIdx.x >> 6);
    int lane = threadIdx.x & 63;
    int orig = perm[j];
    int start = rowptr[orig], end = rowptr[orig + 1];
    float sx = 0.f, sy = 0.f, sz = 0.f, sw = 0.f;
    for (int k = start + lane; k < end; k += 64) {
        int c = rcsr[k].x;
        if (nmap[c] >= 0) {
            sx += coords[c*3+0]; sy += coords[c*3+1]; sz += coords[c*3+2];
            sw += 1.f;
        }
    }
    int cs = colptr[orig], ce = colptr[orig + 1];
    float dg = 0.f;
    for (int k = cs + lane; k < ce; k += 64) {
        if (nmap[ccsr[k]] >= 0) dg += 1.f;
    }
    #pragma unroll
    for (int off = 32; off; off >>= 1) {
        sx += __shfl_xor(sx, off); sy += __shfl_xor(sy, off);
        sz += __shfl_xor(sz, off); sw += __shfl_xor(sw, off);
        dg += __shfl_xor(dg, off);
    }
    if (lane == 0) { nsum2[j] = make_float4(sx, sy, sz, sw); deg2[j] = dg; }
}

// ---------------- stage-2 fused: gather*tanh + delta2(from nsum2) + propagate ----------------
__global__ __launch_bounds__(256)
void k_prop2v(const float* __restrict__ hp, const int* __restrict__ perm,
              const float* __restrict__ tanhv,
              const float4* __restrict__ nsum2, const int* __restrict__ cls2,
              const float* __restrict__ PT, const float* __restrict__ BkT,
              float* __restrict__ out) {
    __shared__ float hT[256];
    int t = threadIdx.x;
    int j = blockIdx.x * 4 + (t >> 6);
    int lane = t & 63;
    int orig = perm[j];
    float tv = tanhv[j];
    float4 s4 = nsum2[j];
    int c = cls2[j];
    const float* P = PT + c * 256;
    float d = s4.x*P[lane] + s4.y*P[64+lane] + s4.z*P[128+lane] + s4.w*P[192+lane];
    float v = hp[orig*64 + lane] * tv + d;
    hT[t] = v;
    __syncthreads();
    float ssum = v;
    #pragma unroll
    for (int off = 32; off; off >>= 1) ssum += __shfl_xor(ssum, off);
    const float* B  = BkT + c * 4096;
    const float* hv = hT + (t & ~63);
    float acc = 0.f;
    #pragma unroll 8
    for (int jj = 0; jj < 64; jj++) acc += B[jj*64 + lane] * hv[jj];
    out[j*64 + lane] = acc + d * ssum;
}

// ---------------- stage-2 agg gather (zero-expanded y2full, single indirection) ----------------
__global__ __launch_bounds__(256)
void k_gagg2(const int* __restrict__ colptr, const int* __restrict__ ccsr,
             const int* __restrict__ perm, const float* __restrict__ y2full,
             float* __restrict__ agg2) {
    int j = blockIdx.x * 4 + (threadIdx.x >> 6);
    int lane = threadIdx.x & 63;
    int orig = perm[j];
    int start = colptr[orig], end = colptr[orig + 1];
    float acc = 0.f;
    #pragma unroll 4
    for (int k = start; k < end; k++) {
        int r = ccsr[k];
        acc += y2full[r*64 + lane];
    }
    agg2[j*64 + lane] = acc;
}

// ---------------- fused stage-2 gn-apply + elu + readout partials ----------------
__global__ __launch_bounds__(256)
void k_gnrd(const float* __restrict__ hs, const float* __restrict__ agg,
            const float* __restrict__ deg2,
            const float* __restrict__ mval, const float* __restrict__ istdv,
            const float* __restrict__ w, const float* __restrict__ b,
            float* __restrict__ part, int CH, int npc) {
    __shared__ float r1[256], r2[256];
    int blk = blockIdx.x;
    int g = blk / CH, chunk = blk % CH;
    int t = threadIdx.x, c = t & 63, grp = t >> 6;
    int n0 = chunk * npc, nend = min(n0 + npc, KP_);
    float mv = mval[g*64 + c], is = istdv[g*64 + c], wv = w[c], bv = b[c];
    float s = 0.f, m = -1e30f;
    for (int n = n0 + grp; n < nend; n += 4) {
        int node = g * KP_ + n;
        float v = hs[node*64 + c] + agg[node*64 + c] / fmaxf(deg2[node], 1.f);
        v = wv * (v - mv) * is + bv;
        v = v > 0.f ? v : expm1f(v);
        s += v; m = fmaxf(m, v);
    }
    r1[t] = s; r2[t] = m;
    __syncthreads();
    if (grp == 0) {
        part[blk*128 + c]      = r1[c] + r1[64+c] + r1[128+c] + r1[192+c];
        part[blk*128 + 64 + c] = fmaxf(fmaxf(r2[c], r2[64+c]), fmaxf(r2[128+c], r2[192+c]));
    }
}

// ---------------- readout finalize: lin1 relu -> lin2 -> log_softmax ----------------
__global__ void k_rfin(const float* __restrict__ part, int CH,
                       const float* __restrict__ l1W, const float* __restrict__ l1b,
                       const float* __restrict__ l2W, const float* __restrict__ l2b,
                       float* __restrict__ out) {
    __shared__ float gv[192], rS[64];
    int g = blockIdx.x, t = threadIdx.x;   // 64 threads
    float s = 0.f, m = -1e30f;
    for (int i = 0; i < CH; i++) {
        s += part[(g*CH + i)*128 + t];
        m = fmaxf(m, part[(g*CH + i)*128 + 64 + t]);
    }
    gv[t] = s / (float)KP_;
    gv[64 + t] = m;
    gv[128 + t] = s;
    __syncthreads();
    float acc = l1b[t];
    for (int k = 0; k < 192; k++) acc += gv[k] * l1W[k*64 + t];
    rS[t] = fmaxf(acc, 0.f);
    __syncthreads();
    if (t == 0) {
        float l0 = l2b[0], l1v = l2b[1];
        for (int hh = 0; hh < 64; hh++) { l0 += rS[hh]*l2W[hh*2+0]; l1v += rS[hh]*l2W[hh*2+1]; }
        float mx  = fmaxf(l0, l1v);
        float lse = mx + logf(expf(l0 - mx) + expf(l1v - mx));
        out[g*2 + 0] = l0  - lse;
        out[g*2 + 1] = l1v - lse;
    }
}

extern "C" void kernel_launch(void* const* d_in, const int* in_sizes, int n_in,
                              void* d_out, int out_size, void* d_ws, size_t ws_size,
                              hipStream_t stream) {
    const float* x      = (const float*)d_in[0];
    const int*   eidx   = (const int*)  d_in[1];
    const float* eattr  = (const float*)d_in[2];
    const float* coords = (const float*)d_in[3];
    const int*   acls   = (const int*)  d_in[4];
    const float* BkTab  = (const float*)d_in[5];
    const float* posW   = (const float*)d_in[6];
    const float* posb   = (const float*)d_in[7];
    const float* W1s    = (const float*)d_in[8];
    const float* W1n    = (const float*)d_in[9];
    const float* b1     = (const float*)d_in[10];
    const float* gn1w   = (const float*)d_in[11];
    const float* gn1b   = (const float*)d_in[12];
    const float* gn1ms  = (const float*)d_in[13];
    const float* poolp  = (const float*)d_in[14];
    const float* W2s    = (const float*)d_in[15];
    const float* W2n    = (const float*)d_in[16];
    const float* b2     = (const float*)d_in[17];
    const float* gn2w   = (const float*)d_in[18];
    const float* gn2b   = (const float*)d_in[19];
    const float* gn2ms  = (const float*)d_in[20];
    const float* l1W    = (const float*)d_in[21];
    const float* l1b    = (const float*)d_in[22];
    const float* l2W    = (const float*)d_in[23];
    const float* l2b    = (const float*)d_in[24];

    const int* row  = eidx;
    const int* colp = eidx + ET_;

    float* W = (float*)d_ws;
    const size_t NTH = (size_t)NT_ * 64;        // 2,097,152 floats
    float* b0    = W;                           // y -> y2full
    float* b1buf = W + 1*NTH;                   // hself -> hp(in-place) -> agg2
    float* b2buf = W + 2*NTH;                   // agg -> hp2
    float* b3buf = W + 3*NTH;                   // nsum / nsum2 alias -> hs2
    float* p = W + 4*NTH;
    int2*  rowcsr = (int2*)p;        p += 2*(size_t)ET_;   // 8 MB
    int*   colcsr = (int*)p;         p += ET_;             // 4 MB
    int*   rowptr = (int*)p;         p += NT_ + 8;
    int*   colptr = (int*)p;         p += NT_ + 8;
    int*   histR  = (int*)p;         p += NT_;             // becomes cursR; partials alias
    int*   histC  = (int*)p;         p += NT_;             // becomes cursC
    float* deg    = p;               p += NT_;
    float* deg2   = p;               p += NP2_;
    float* tanhv  = p;               p += NP2_;
    int*   perm   = (int*)p;         p += NP2_;
    int*   nmap   = (int*)p;         p += NT_;
    int*   cls2   = (int*)p;         p += NP2_;
    float* BkT    = p;               p += 6 * 4096;
    float* PT     = p;               p += 6 * 256;
    float* meanv  = p;               p += G_ * 64;
    float* istdv  = p;               p += G_ * 64;
    float* partial= (float*)histR;                         // alias (free after k_scatter... used from gnstat on)
    float4* nsum  = (float4*)b3buf;                        // stage-1 (live nsum1..gnprop)
    float4* nsum2 = (float4*)b3buf;                        // stage-2 (live s2pre..prop2v; hs2 written after)

    // ---- prep ----
    hipMemsetAsync(histR, 0, 2 * NT_ * sizeof(int), stream);   // histR + histC
    hipMemsetAsync(nmap, 0xFF, NT_ * sizeof(int), stream);
    k_bkT      <<<96,       256, 0, stream>>>(BkTab, BkT);
    k_pre      <<<6,        256, 0, stream>>>(BkTab, posW, posb, PT);
    k_hist     <<<G_*BPB_,  256, 0, stream>>>(row, colp, histR, histC);
    k_scan     <<<G_,       256, 0, stream>>>(histR, histC, rowptr, colptr, deg);
    k_scatter  <<<G_*BPB_,  256, 0, stream>>>(row, colp, eattr, histR, histC,
                                              rowcsr, colcsr);

    // ---- stage 1 ----
    k_gemm_dual<<<NT_/32,  256, 0, stream>>>(x, FIN_, W1n, W1s, b1, nullptr,
                                             b0 /*y*/, b1buf /*hself*/);
    k_nsum1    <<<NT_/4,   256, 0, stream>>>(rowptr, rowcsr, coords, nsum);
    k_gagg     <<<NT_/4,   256, 0, stream>>>(colptr, colcsr, b0 /*y*/, b2buf /*agg*/);
    k_gnstat   <<<G_*8,    256, 0, stream>>>(b1buf /*hself*/, b2buf /*agg*/, deg,
                                             partial, N_, 8, 64);
    k_gnfin    <<<G_,      64,  0, stream>>>(partial, gn1ms, 8, N_, meanv, istdv);
    k_gnprop   <<<NT_/4,   256, 0, stream>>>(b1buf /*hself*/, b2buf /*agg*/, deg,
                                             meanv, istdv, gn1w, gn1b,
                                             nsum, acls, PT, BkT,
                                             b1buf /*hp in-place*/);
    k_topk     <<<G_,      512, 0, stream>>>(b1buf /*hp*/, poolp, acls,
                                             perm, tanhv, nmap, cls2);

    // ---- stage 2 ----
    k_s2pre    <<<NP2_/4,  256, 0, stream>>>(rowptr, rowcsr, colptr, colcsr,
                                             perm, nmap, coords, nsum2, deg2);
    k_prop2v   <<<NP2_/4,  256, 0, stream>>>(b1buf /*hp*/, perm, tanhv,
                                             nsum2, cls2, PT, BkT, b2buf /*hp2*/);
    hipMemsetAsync(b0, 0, NTH * sizeof(float), stream);        // y2full zero
    k_gemm_dual<<<NP2_/32, 256, 0, stream>>>(b2buf /*hp2*/, 64, W2n, W2s, b2, perm,
                                             b0 /*y2full scattered*/, b3buf /*hs2*/);
    k_gagg2    <<<NP2_/4,  256, 0, stream>>>(colptr, colcsr, perm, b0 /*y2full*/,
                                             b1buf /*agg2*/);
    k_gnstat   <<<G_*6,    256, 0, stream>>>(b3buf /*hs2*/, b1buf /*agg2*/, deg2,
                                             partial, KP_, 6, 60);
    k_gnfin    <<<G_,      64,  0, stream>>>(partial, gn2ms, 6, KP_, meanv, istdv);
    k_gnrd     <<<G_*6,    256, 0, stream>>>(b3buf /*hs2*/, b1buf /*agg2*/, deg2,
                                             meanv, istdv, gn2w, gn2b,
                                             partial, 6, 60);
    k_rfin     <<<G_,      64,  0, stream>>>(partial, 6, l1W, l1b, l2W, l2b,
                                             (float*)d_out);
}